// Round 6
// baseline (1097.103 us; speedup 1.0000x reference)
//
#include <hip/hip_runtime.h>
#include <hip/hip_bf16.h>
#include <math.h>

// Problem constants
#define D_MODEL 512
#define D_STATE 16
#define D_CONV  4
#define D_INNER 1024
#define DT_RANK 32
#define BB      4
#define NN      576
#define TOK     (BB*NN)   // 2304 tokens

// ---------------------------------------------------------------------------
// LayerNorm: one wave (64 threads) per token of 512 elems
// ---------------------------------------------------------------------------
__global__ __launch_bounds__(64) void ln_kernel(const float* __restrict__ x,
                                                const float* __restrict__ g,
                                                const float* __restrict__ b,
                                                float* __restrict__ o) {
    int t = blockIdx.x;
    int lane = threadIdx.x;
    const float* xr = x + (size_t)t * D_MODEL;
    float4 v0 = ((const float4*)xr)[lane];        // elems 4*lane .. +3
    float4 v1 = ((const float4*)xr)[64 + lane];   // elems 256+4*lane .. +3
    float s = v0.x + v0.y + v0.z + v0.w + v1.x + v1.y + v1.z + v1.w;
    #pragma unroll
    for (int m = 32; m; m >>= 1) s += __shfl_xor(s, m);
    float mean = s * (1.0f / D_MODEL);
    float dx[8] = {v0.x-mean, v0.y-mean, v0.z-mean, v0.w-mean,
                   v1.x-mean, v1.y-mean, v1.z-mean, v1.w-mean};
    float q = 0.f;
    #pragma unroll
    for (int i = 0; i < 8; i++) q += dx[i]*dx[i];
    #pragma unroll
    for (int m = 32; m; m >>= 1) q += __shfl_xor(q, m);
    float rstd = rsqrtf(q * (1.0f / D_MODEL) + 1e-5f);
    float4 g0 = ((const float4*)g)[lane], g1 = ((const float4*)g)[64 + lane];
    float4 b0 = ((const float4*)b)[lane], b1 = ((const float4*)b)[64 + lane];
    float4 o0, o1;
    o0.x = dx[0]*rstd*g0.x + b0.x; o0.y = dx[1]*rstd*g0.y + b0.y;
    o0.z = dx[2]*rstd*g0.z + b0.z; o0.w = dx[3]*rstd*g0.w + b0.w;
    o1.x = dx[4]*rstd*g1.x + b1.x; o1.y = dx[5]*rstd*g1.y + b1.y;
    o1.z = dx[6]*rstd*g1.z + b1.z; o1.w = dx[7]*rstd*g1.w + b1.w;
    float* orow = o + (size_t)t * D_MODEL;
    ((float4*)orow)[lane] = o0;
    ((float4*)orow)[64 + lane] = o1;
}

#define EP_NONE     0
#define EP_SOFTPLUS 1
#define EP_GELU     2
#define EP_BIAS_ADD 3

// ---------------------------------------------------------------------------
// Tiled fp32 GEMM (64x64x32, 4x4 micro-tile):  C[m,n] = sum_k A[m,k]*W[n,k]
// W row-major NxK. M%64==0, N%64==0, K%32==0.
// ---------------------------------------------------------------------------
template<int EP>
__global__ __launch_bounds__(256) void gemm_nt(
        const float* __restrict__ A, int lda,
        const float* __restrict__ W,
        float* __restrict__ C, int ldc,
        const float* __restrict__ bias,
        const float* __restrict__ add, int ldadd,
        int M, int N, int K) {
    __shared__ float As[32][68];  // [kk][m] transposed, padded
    __shared__ float Bs[32][68];  // [kk][n]
    int tid = threadIdx.x;
    int tx = tid & 15, ty = tid >> 4;
    int m0 = blockIdx.y * 64, n0 = blockIdx.x * 64;
    int arow = tid >> 3;          // 0..31
    int acol = (tid & 7) * 4;     // 0,4,...,28
    float acc[4][4] = {};

    for (int k0 = 0; k0 < K; k0 += 32) {
        float4 a0 = *(const float4*)&A[(size_t)(m0 + arow) * lda + k0 + acol];
        float4 a1 = *(const float4*)&A[(size_t)(m0 + arow + 32) * lda + k0 + acol];
        float4 w0 = *(const float4*)&W[(size_t)(n0 + arow) * K + k0 + acol];
        float4 w1 = *(const float4*)&W[(size_t)(n0 + arow + 32) * K + k0 + acol];
        __syncthreads();   // previous tile fully consumed
        As[acol + 0][arow] = a0.x; As[acol + 1][arow] = a0.y;
        As[acol + 2][arow] = a0.z; As[acol + 3][arow] = a0.w;
        As[acol + 0][arow + 32] = a1.x; As[acol + 1][arow + 32] = a1.y;
        As[acol + 2][arow + 32] = a1.z; As[acol + 3][arow + 32] = a1.w;
        Bs[acol + 0][arow] = w0.x; Bs[acol + 1][arow] = w0.y;
        Bs[acol + 2][arow] = w0.z; Bs[acol + 3][arow] = w0.w;
        Bs[acol + 0][arow + 32] = w1.x; Bs[acol + 1][arow + 32] = w1.y;
        Bs[acol + 2][arow + 32] = w1.z; Bs[acol + 3][arow + 32] = w1.w;
        __syncthreads();
        #pragma unroll
        for (int kk = 0; kk < 32; kk++) {
            float av[4], bv[4];
            *(float4*)&av[0] = *(const float4*)&As[kk][ty * 4];
            *(float4*)&bv[0] = *(const float4*)&Bs[kk][tx * 4];
            #pragma unroll
            for (int i = 0; i < 4; i++)
                #pragma unroll
                for (int j = 0; j < 4; j++)
                    acc[i][j] = fmaf(av[i], bv[j], acc[i][j]);
        }
    }

    int mbase = m0 + ty * 4, nbase = n0 + tx * 4;
    #pragma unroll
    for (int i = 0; i < 4; i++) {
        float vv[4];
        #pragma unroll
        for (int j = 0; j < 4; j++) {
            float v = acc[i][j];
            if (EP == EP_SOFTPLUS) {
                v += bias[nbase + j];
                v = fmaxf(v, 0.f) + log1pf(expf(-fabsf(v)));
            } else if (EP == EP_GELU) {
                v += bias[nbase + j];
                float u = v;
                v = 0.5f * u * (1.f + tanhf(0.7978845608028654f * (u + 0.044715f * u * u * u)));
            } else if (EP == EP_BIAS_ADD) {
                v += bias[nbase + j];
                v += add[(size_t)(mbase + i) * ldadd + nbase + j];
            }
            vv[j] = v;
        }
        *(float4*)&C[(size_t)(mbase + i) * ldc + nbase] =
            make_float4(vv[0], vv[1], vv[2], vv[3]);
    }
}

// ---------------------------------------------------------------------------
// Split-K GEMM specialized for the Wx projection: M=2304, N=64, K=1024,
// 4 K-slices of 256 via blockIdx.z. Partial sums to Cpart[z][M][64].
// Identical tile structure to gemm_nt (64x64x32, 4x4 micro-tile).
// ---------------------------------------------------------------------------
__global__ __launch_bounds__(256) void gemm_wx_splitk(
        const float* __restrict__ A,      // [TOK][1024]
        const float* __restrict__ W,      // [64][1024]
        float* __restrict__ Cpart) {      // [4][TOK][64]
    __shared__ float As[32][68];
    __shared__ float Bs[32][68];
    int tid = threadIdx.x;
    int tx = tid & 15, ty = tid >> 4;
    int m0 = blockIdx.y * 64;
    int z = blockIdx.z;                   // K-slice
    const float* Az = A + z * 256;
    const float* Wz = W + z * 256;
    int arow = tid >> 3;
    int acol = (tid & 7) * 4;
    float acc[4][4] = {};

    for (int k0 = 0; k0 < 256; k0 += 32) {
        float4 a0 = *(const float4*)&Az[(size_t)(m0 + arow) * 1024 + k0 + acol];
        float4 a1 = *(const float4*)&Az[(size_t)(m0 + arow + 32) * 1024 + k0 + acol];
        float4 w0 = *(const float4*)&Wz[(size_t)(arow) * 1024 + k0 + acol];
        float4 w1 = *(const float4*)&Wz[(size_t)(arow + 32) * 1024 + k0 + acol];
        __syncthreads();
        As[acol + 0][arow] = a0.x; As[acol + 1][arow] = a0.y;
        As[acol + 2][arow] = a0.z; As[acol + 3][arow] = a0.w;
        As[acol + 0][arow + 32] = a1.x; As[acol + 1][arow + 32] = a1.y;
        As[acol + 2][arow + 32] = a1.z; As[acol + 3][arow + 32] = a1.w;
        Bs[acol + 0][arow] = w0.x; Bs[acol + 1][arow] = w0.y;
        Bs[acol + 2][arow] = w0.z; Bs[acol + 3][arow] = w0.w;
        Bs[acol + 0][arow + 32] = w1.x; Bs[acol + 1][arow + 32] = w1.y;
        Bs[acol + 2][arow + 32] = w1.z; Bs[acol + 3][arow + 32] = w1.w;
        __syncthreads();
        #pragma unroll
        for (int kk = 0; kk < 32; kk++) {
            float av[4], bv[4];
            *(float4*)&av[0] = *(const float4*)&As[kk][ty * 4];
            *(float4*)&bv[0] = *(const float4*)&Bs[kk][tx * 4];
            #pragma unroll
            for (int i = 0; i < 4; i++)
                #pragma unroll
                for (int j = 0; j < 4; j++)
                    acc[i][j] = fmaf(av[i], bv[j], acc[i][j]);
        }
    }

    float* Cz = Cpart + (size_t)z * TOK * 64;
    int mbase = m0 + ty * 4, nbase = tx * 4;
    #pragma unroll
    for (int i = 0; i < 4; i++)
        *(float4*)&Cz[(size_t)(mbase + i) * 64 + nbase] =
            make_float4(acc[i][0], acc[i][1], acc[i][2], acc[i][3]);
}

// Reduce 4 K-slice partials: xd[i] = sum_z Cpart[z][i], i < TOK*64
__global__ __launch_bounds__(256) void reduce4_kernel(
        const float* __restrict__ Cpart, float* __restrict__ xd) {
    int i = blockIdx.x * 256 + threadIdx.x;
    const int M64 = TOK * 64;
    xd[i] = Cpart[i] + Cpart[M64 + i] + Cpart[2 * M64 + i] + Cpart[3 * M64 + i];
}

// ---------------------------------------------------------------------------
// Tiled fp32 GEMM (128x128x16, 8x8 micro-tile as 2x2 blocks of 4x4).
// Halves LDS bytes per FLOP vs the 64x64 kernel. M%128==0, N%128==0, K%16==0.
// ---------------------------------------------------------------------------
template<int EP>
__global__ __launch_bounds__(256) void gemm_nt_128(
        const float* __restrict__ A, int lda,
        const float* __restrict__ W,
        float* __restrict__ C, int ldc,
        const float* __restrict__ bias,
        int M, int N, int K) {
    __shared__ float As[16][132];
    __shared__ float Bs[16][132];
    int tid = threadIdx.x;
    int tx = tid & 15, ty = tid >> 4;
    int m0 = blockIdx.y * 128, n0 = blockIdx.x * 128;
    int lrow = tid >> 1;            // 0..127
    int lcol = (tid & 1) * 8;       // 0 or 8
    float acc[8][8] = {};

    for (int k0 = 0; k0 < K; k0 += 16) {
        float4 a0 = *(const float4*)&A[(size_t)(m0 + lrow) * lda + k0 + lcol];
        float4 a1 = *(const float4*)&A[(size_t)(m0 + lrow) * lda + k0 + lcol + 4];
        float4 w0 = *(const float4*)&W[(size_t)(n0 + lrow) * K + k0 + lcol];
        float4 w1 = *(const float4*)&W[(size_t)(n0 + lrow) * K + k0 + lcol + 4];
        __syncthreads();
        As[lcol + 0][lrow] = a0.x; As[lcol + 1][lrow] = a0.y;
        As[lcol + 2][lrow] = a0.z; As[lcol + 3][lrow] = a0.w;
        As[lcol + 4][lrow] = a1.x; As[lcol + 5][lrow] = a1.y;
        As[lcol + 6][lrow] = a1.z; As[lcol + 7][lrow] = a1.w;
        Bs[lcol + 0][lrow] = w0.x; Bs[lcol + 1][lrow] = w0.y;
        Bs[lcol + 2][lrow] = w0.z; Bs[lcol + 3][lrow] = w0.w;
        Bs[lcol + 4][lrow] = w1.x; Bs[lcol + 5][lrow] = w1.y;
        Bs[lcol + 6][lrow] = w1.z; Bs[lcol + 7][lrow] = w1.w;
        __syncthreads();
        #pragma unroll
        for (int kk = 0; kk < 16; kk++) {
            float av[8], bv[8];
            *(float4*)&av[0] = *(const float4*)&As[kk][ty * 4];
            *(float4*)&av[4] = *(const float4*)&As[kk][64 + ty * 4];
            *(float4*)&bv[0] = *(const float4*)&Bs[kk][tx * 4];
            *(float4*)&bv[4] = *(const float4*)&Bs[kk][64 + tx * 4];
            #pragma unroll
            for (int i = 0; i < 8; i++)
                #pragma unroll
                for (int j = 0; j < 8; j++)
                    acc[i][j] = fmaf(av[i], bv[j], acc[i][j]);
        }
    }

    #pragma unroll
    for (int hi = 0; hi < 2; hi++) {
        #pragma unroll
        for (int i = 0; i < 4; i++) {
            int row = m0 + hi * 64 + ty * 4 + i;
            #pragma unroll
            for (int hj = 0; hj < 2; hj++) {
                int col = n0 + hj * 64 + tx * 4;
                float vv[4];
                #pragma unroll
                for (int j = 0; j < 4; j++) {
                    float v = acc[hi * 4 + i][hj * 4 + j];
                    if (EP == EP_GELU) {
                        v += bias[col + j];
                        float u = v;
                        v = 0.5f * u * (1.f + tanhf(0.7978845608028654f * (u + 0.044715f * u * u * u)));
                    }
                    vv[j] = v;
                }
                *(float4*)&C[(size_t)row * ldc + col] =
                    make_float4(vv[0], vv[1], vv[2], vv[3]);
            }
        }
    }
}

// ---------------------------------------------------------------------------
// Depthwise causal conv1d (k=4) + bias + SiLU.
// dir=0: forward. dir=1: reverse direction in ORIGINAL sequence coords.
// u lives in xz buffer (row stride 2*D_INNER), cols 0..D_INNER-1.
// ---------------------------------------------------------------------------
__global__ __launch_bounds__(256) void conv_silu_kernel(
        const float* __restrict__ xz, const float* __restrict__ w,
        const float* __restrict__ cb, float* __restrict__ out, int dir) {
    int idx = blockIdx.x * 256 + threadIdx.x;       // TOK * D_INNER total
    int c = idx & (D_INNER - 1);
    int t = idx >> 10;
    int b = t / NN, n = t % NN;
    const float* up = xz + (size_t)b * NN * (2 * D_INNER) + c;
    float4 wv = *(const float4*)&w[c * 4];
    float acc;
    if (dir == 0) {
        acc =                 up[(size_t)n * (2*D_INNER)] * wv.w;
        if (n >= 1) acc = fmaf(up[(size_t)(n-1) * (2*D_INNER)], wv.z, acc);
        if (n >= 2) acc = fmaf(up[(size_t)(n-2) * (2*D_INNER)], wv.y, acc);
        if (n >= 3) acc = fmaf(up[(size_t)(n-3) * (2*D_INNER)], wv.x, acc);
    } else {
        acc =                    up[(size_t)n * (2*D_INNER)] * wv.w;
        if (n+1 < NN) acc = fmaf(up[(size_t)(n+1) * (2*D_INNER)], wv.z, acc);
        if (n+2 < NN) acc = fmaf(up[(size_t)(n+2) * (2*D_INNER)], wv.y, acc);
        if (n+3 < NN) acc = fmaf(up[(size_t)(n+3) * (2*D_INNER)], wv.x, acc);
    }
    float v = acc + cb[c];
    out[(size_t)t * D_INNER + c] = v / (1.f + expf(-v));
}

// ---------------------------------------------------------------------------
// Selective scan, time-batched by 16 (576 = 36*16, no tail).
// One wave handles 4 consecutive d-channels x 16 states.
// lane: s = lane&15 (state), dl = lane>>4 (d within group of 4).
// dir=0: n = 0..N-1 ; dir=1: n = N-1..0.
// Per 16-step block: issue all 64 loads (independent, pipelined), run the 16
// dependent h-FMAs back-to-back, then reduce with 4 rounds x 16 INDEPENDENT
// shuffles (pipelined) instead of 4 serial shuffles per step.
// y may alias u: all reads of a block complete before its writes; waves own
// disjoint d channels.  y = (sum_s h*C) + u*D, then * silu(z).
// ---------------------------------------------------------------------------
__global__ __launch_bounds__(256) void scan_kernel(
        const float* __restrict__ dt, const float* __restrict__ xdbl,
        const float* __restrict__ u, const float* __restrict__ xz,
        const float* __restrict__ Alog, const float* __restrict__ Dp,
        float* __restrict__ y, int dir) {
    int lane = threadIdx.x & 63;
    int wave = threadIdx.x >> 6;
    int w = blockIdx.x * 4 + wave;        // 0..1023
    int s = lane & 15;
    int dl = lane >> 4;
    int b = w >> 8;                        // 0..3
    int d = (w & 255) * 4 + dl;            // 0..1023
    float A_ds = -expf(Alog[d * D_STATE + s]);
    float Dd = Dp[d];
    float h = 0.f;
    const int UF = 16;
    for (int i0 = 0; i0 < NN; i0 += UF) {
        float dtv[UF], uv[UF], Bv[UF], Cv[UF];
        #pragma unroll
        for (int j = 0; j < UF; j++) {
            int i = i0 + j;
            int n = dir ? (NN - 1 - i) : i;
            size_t tt = (size_t)b * NN + n;
            dtv[j] = dt[tt * D_INNER + d];
            uv[j]  = u[tt * D_INNER + d];
            Bv[j]  = xdbl[tt * 64 + 32 + s];
            Cv[j]  = xdbl[tt * 64 + 48 + s];
        }
        float p[UF];
        #pragma unroll
        for (int j = 0; j < UF; j++) {
            float dA = expf(dtv[j] * A_ds);
            h = fmaf(dA, h, dtv[j] * Bv[j] * uv[j]);
            p[j] = h * Cv[j];
        }
        #pragma unroll
        for (int j = 0; j < UF; j++) {
            p[j] += __shfl_xor(p[j], 1);
            p[j] += __shfl_xor(p[j], 2);
            p[j] += __shfl_xor(p[j], 4);
            p[j] += __shfl_xor(p[j], 8);
        }
        if (s == 0) {
            #pragma unroll
            for (int j = 0; j < UF; j++) {
                int i = i0 + j;
                int n = dir ? (NN - 1 - i) : i;
                size_t tt = (size_t)b * NN + n;
                float zv = xz[tt * (2 * D_INNER) + D_INNER + d];
                float yv = p[j] + uv[j] * Dd;
                yv *= zv / (1.f + expf(-zv));
                y[tt * D_INNER + d] = yv;
            }
        }
    }
}

// ---------------------------------------------------------------------------
extern "C" void kernel_launch(void* const* d_in, const int* in_sizes, int n_in,
                              void* d_out, int out_size, void* d_ws, size_t ws_size,
                              hipStream_t stream) {
    const float* x       = (const float*)d_in[0];
    const float* g1      = (const float*)d_in[1];
    const float* b1      = (const float*)d_in[2];
    const float* g2      = (const float*)d_in[3];
    const float* b2      = (const float*)d_in[4];
    const float* merge_W = (const float*)d_in[5];
    const float* merge_b = (const float*)d_in[6];
    const float* ffn_W1  = (const float*)d_in[7];
    const float* ffn_b1  = (const float*)d_in[8];
    const float* ffn_W2  = (const float*)d_in[9];
    const float* ffn_b2  = (const float*)d_in[10];
    const float* Win[2]   = {(const float*)d_in[11], (const float*)d_in[20]};
    const float* convw[2] = {(const float*)d_in[12], (const float*)d_in[21]};
    const float* convb[2] = {(const float*)d_in[13], (const float*)d_in[22]};
    const float* Wx[2]    = {(const float*)d_in[14], (const float*)d_in[23]};
    const float* Wdt[2]   = {(const float*)d_in[15], (const float*)d_in[24]};
    const float* bdt[2]   = {(const float*)d_in[16], (const float*)d_in[25]};
    const float* Alog[2]  = {(const float*)d_in[17], (const float*)d_in[26]};
    const float* Dp[2]    = {(const float*)d_in[18], (const float*)d_in[27]};
    const float* Wout[2]  = {(const float*)d_in[19], (const float*)d_in[28]};
    float* out = (float*)d_out;

    // workspace layout (floats) — both directions share one buffer set
    float* ws = (float*)d_ws;
    const size_t T = TOK;
    float* xn  = ws;                       // T*512   (reused as xn2 later)
    float* xz  = xn  + T * 512;            // T*2048  (reused as FFN hidden)
    float* uc  = xz  + T * 2048;           // T*1024  (y aliases)
    float* xd  = uc  + T * 1024;           // T*64
    float* dt  = xd  + T * 64;             // T*1024
    float* xfb = dt  + T * 1024;           // T*1024  (concat xf|xb)
    float* x2  = xfb + T * 1024;           // T*512
    // xd4 (split-K partials, 4*T*64 = 589824 floats) aliases x2 (T*512 =
    // 1179648 floats): last xd4 use is step 4 of p=1; x2 first written step 8.
    float* xd4 = x2;
    // total: 6208 floats/token * 2304 tok * 4 B = 57.2 MB

    // 1. LN1
    ln_kernel<<<TOK, 64, 0, stream>>>(x, g1, b1, xn);

    for (int p = 0; p < 2; p++) {
        // 2. xz = xn @ Win^T   (T x 2048)
        gemm_nt_128<EP_NONE><<<dim3(2048/128, TOK/128), 256, 0, stream>>>(
            xn, 512, Win[p], xz, 2048, nullptr, TOK, 2048, 512);
        // 3. conv + silu -> uc
        conv_silu_kernel<<<TOK * D_INNER / 256, 256, 0, stream>>>(
            xz, convw[p], convb[p], uc, p);
        // 4. x_dbl = uc @ Wx^T  (T x 64), split-K x4 + reduce
        gemm_wx_splitk<<<dim3(1, TOK/64, 4), 256, 0, stream>>>(uc, Wx[p], xd4);
        reduce4_kernel<<<TOK * 64 / 256, 256, 0, stream>>>(xd4, xd);
        // 5. dt = softplus(dt_raw @ Wdt^T + bdt)  (T x 1024); dt_raw = cols 0..31
        gemm_nt<EP_SOFTPLUS><<<dim3(1024/64, TOK/64), 256, 0, stream>>>(
            xd, 64, Wdt[p], dt, 1024, bdt[p], nullptr, 0, TOK, 1024, 32);
        // 6. selective scan (+ u*D, * silu(z)); y aliases uc
        scan_kernel<<<256, 256, 0, stream>>>(
            dt, xd, uc, xz, Alog[p], Dp[p], uc, p);
        // 7. xf/xb = y @ Wout^T  (T x 512) -> halves of xfb
        gemm_nt<EP_NONE><<<dim3(512/64, TOK/64), 256, 0, stream>>>(
            uc, 1024, Wout[p], xfb + p * 512, 1024, nullptr, nullptr, 0, TOK, 512, 1024);
    }

    // 8. x2 = x + [xf|xb] @ merge_W^T + merge_b
    gemm_nt<EP_BIAS_ADD><<<dim3(512/64, TOK/64), 256, 0, stream>>>(
        xfb, 1024, merge_W, x2, 512, merge_b, x, 512, TOK, 512, 1024);

    // 9. LN2 (xn buffer reused)
    ln_kernel<<<TOK, 64, 0, stream>>>(x2, g2, b2, xn);

    // 10. h = gelu(xn2 @ ffn_W1^T + b1)   (T x 2048), reuse xz
    gemm_nt_128<EP_GELU><<<dim3(2048/128, TOK/128), 256, 0, stream>>>(
        xn, 512, ffn_W1, xz, 2048, ffn_b1, TOK, 2048, 512);

    // 11. out = x2 + h @ ffn_W2^T + b2
    gemm_nt<EP_BIAS_ADD><<<dim3(512/64, TOK/64), 256, 0, stream>>>(
        xz, 2048, ffn_W2, out, 512, ffn_b2, x2, 512, TOK, 512, 2048);
}

// Round 10
// 671.195 us; speedup vs baseline: 1.6346x; 1.6346x over previous
//
#include <hip/hip_runtime.h>
#include <hip/hip_bf16.h>
#include <math.h>

// Problem constants
#define D_MODEL 512
#define D_STATE 16
#define D_CONV  4
#define D_INNER 1024
#define DT_RANK 32
#define BB      4
#define NN      576
#define TOK     (BB*NN)   // 2304 tokens

// Fast device math: native v_exp_f32/v_log_f32 (~2 ulp; baseline absmax
// 0.0156 passed with libm, so these deltas are free).
__device__ __forceinline__ float fexp(float x)  { return __expf(x); }
__device__ __forceinline__ float fsilu(float x) { return x / (1.f + __expf(-x)); }
__device__ __forceinline__ float fsoftplus(float x) {
    return fmaxf(x, 0.f) + __logf(1.f + __expf(-fabsf(x)));
}
__device__ __forceinline__ float fgelu(float u) {
    float a = 0.7978845608028654f * (u + 0.044715f * u * u * u);
    float t = 1.f - 2.f / (1.f + __expf(2.f * a));   // tanh(a)
    return 0.5f * u * (1.f + t);
}

// ---------------------------------------------------------------------------
// LayerNorm: one wave per token of 512 elems
// ---------------------------------------------------------------------------
__global__ __launch_bounds__(64) void ln_kernel(const float* __restrict__ x,
                                                const float* __restrict__ g,
                                                const float* __restrict__ b,
                                                float* __restrict__ o) {
    int t = blockIdx.x;
    int lane = threadIdx.x;
    const float* xr = x + (size_t)t * D_MODEL;
    float4 v0 = ((const float4*)xr)[lane];
    float4 v1 = ((const float4*)xr)[64 + lane];
    float s = v0.x + v0.y + v0.z + v0.w + v1.x + v1.y + v1.z + v1.w;
    #pragma unroll
    for (int m = 32; m; m >>= 1) s += __shfl_xor(s, m);
    float mean = s * (1.0f / D_MODEL);
    float dx[8] = {v0.x-mean, v0.y-mean, v0.z-mean, v0.w-mean,
                   v1.x-mean, v1.y-mean, v1.z-mean, v1.w-mean};
    float q = 0.f;
    #pragma unroll
    for (int i = 0; i < 8; i++) q += dx[i]*dx[i];
    #pragma unroll
    for (int m = 32; m; m >>= 1) q += __shfl_xor(q, m);
    float rstd = rsqrtf(q * (1.0f / D_MODEL) + 1e-5f);
    float4 g0 = ((const float4*)g)[lane], g1 = ((const float4*)g)[64 + lane];
    float4 b0 = ((const float4*)b)[lane], b1 = ((const float4*)b)[64 + lane];
    float4 o0, o1;
    o0.x = dx[0]*rstd*g0.x + b0.x; o0.y = dx[1]*rstd*g0.y + b0.y;
    o0.z = dx[2]*rstd*g0.z + b0.z; o0.w = dx[3]*rstd*g0.w + b0.w;
    o1.x = dx[4]*rstd*g1.x + b1.x; o1.y = dx[5]*rstd*g1.y + b1.y;
    o1.z = dx[6]*rstd*g1.z + b1.z; o1.w = dx[7]*rstd*g1.w + b1.w;
    float* orow = o + (size_t)t * D_MODEL;
    ((float4*)orow)[lane] = o0;
    ((float4*)orow)[64 + lane] = o1;
}

#define EP_NONE     0
#define EP_SOFTPLUS 1
#define EP_GELU     2
#define EP_BIAS_ADD 3

// ---------------------------------------------------------------------------
// MFMA bf16x3-split GEMM: C[m,n] = sum_k A[m,k]*W[n,k]  (fp32-equivalent
// accuracy: A,W split into hi+lo bf16; D += Ahi*Bhi + Ahi*Blo + Alo*Bhi).
// Tile 64x64x32, 4 waves; wave (wm,wn) owns a 32x32 quadrant = 2x2 MFMA tiles.
// Layout bet (A/B frags): lane l holds row/col (l&15), k = (l>>4)*8 + 0..7.
// C/D layout (HW-verified): col = lane&15, row = (lane>>4)*4 + reg.
// LDS: [64][40] bf16 per (operand, hi/lo): 80B row stride -> 16B-aligned
// b128, <=4-way bank alias on reads (not the critical path; split8 is).
// ---------------------------------------------------------------------------
typedef __attribute__((ext_vector_type(8))) short bf16x8;
typedef __attribute__((ext_vector_type(4))) float f32x4;

__device__ __forceinline__ void split8(float4 q0, float4 q1,
                                       uint4 &hi, uint4 &lo) {
    float f[8] = {q0.x, q0.y, q0.z, q0.w, q1.x, q1.y, q1.z, q1.w};
    unsigned hb[8], lb[8];
    #pragma unroll
    for (int i = 0; i < 8; i++) {
        unsigned u = __float_as_uint(f[i]);
        unsigned r = (u + 0x7FFFu + ((u >> 16) & 1u)) >> 16;  // bf16 RNE
        hb[i] = r & 0xFFFFu;
        float lf = f[i] - __uint_as_float(r << 16);
        unsigned ul = __float_as_uint(lf);
        lb[i] = ((ul + 0x7FFFu + ((ul >> 16) & 1u)) >> 16) & 0xFFFFu;
    }
    hi = make_uint4(hb[0]|(hb[1]<<16), hb[2]|(hb[3]<<16),
                    hb[4]|(hb[5]<<16), hb[6]|(hb[7]<<16));
    lo = make_uint4(lb[0]|(lb[1]<<16), lb[2]|(lb[3]<<16),
                    lb[4]|(lb[5]<<16), lb[6]|(lb[7]<<16));
}

template<int EP>
__global__ __launch_bounds__(256) void gemm_mfma(
        const float* __restrict__ A, int lda,
        const float* __restrict__ W,
        float* __restrict__ C, int ldc,
        const float* __restrict__ bias,
        const float* __restrict__ add, int ldadd,
        int N, int K) {
    __shared__ short AsH[64][40], AsL[64][40], BsH[64][40], BsL[64][40];
    int tid  = threadIdx.x;
    int lane = tid & 63;
    int wave = tid >> 6;
    int wm = wave >> 1, wn = wave & 1;
    int m0 = blockIdx.y * 64, n0 = blockIdx.x * 64;
    int srow = tid >> 2;            // 0..63 staging row
    int skb  = (tid & 3) * 8;       // k-offset 0,8,16,24

    f32x4 acc[2][2] = {};

    for (int k0 = 0; k0 < K; k0 += 32) {
        float4 a0 = *(const float4*)&A[(size_t)(m0 + srow) * lda + k0 + skb];
        float4 a1 = *(const float4*)&A[(size_t)(m0 + srow) * lda + k0 + skb + 4];
        float4 w0 = *(const float4*)&W[(size_t)(n0 + srow) * K + k0 + skb];
        float4 w1 = *(const float4*)&W[(size_t)(n0 + srow) * K + k0 + skb + 4];
        uint4 ah, al, bh, bl;
        split8(a0, a1, ah, al);
        split8(w0, w1, bh, bl);
        __syncthreads();            // previous tile fully consumed
        *(uint4*)&AsH[srow][skb] = ah;
        *(uint4*)&AsL[srow][skb] = al;
        *(uint4*)&BsH[srow][skb] = bh;
        *(uint4*)&BsL[srow][skb] = bl;
        __syncthreads();

        int hk = (lane >> 4) * 8;
        int rr = lane & 15;
        bf16x8 fAh[2], fAl[2], fBh[2], fBl[2];
        #pragma unroll
        for (int mi = 0; mi < 2; mi++) {
            int r = wm * 32 + mi * 16 + rr;
            fAh[mi] = *(const bf16x8*)&AsH[r][hk];
            fAl[mi] = *(const bf16x8*)&AsL[r][hk];
        }
        #pragma unroll
        for (int ni = 0; ni < 2; ni++) {
            int c = wn * 32 + ni * 16 + rr;
            fBh[ni] = *(const bf16x8*)&BsH[c][hk];
            fBl[ni] = *(const bf16x8*)&BsL[c][hk];
        }
        #pragma unroll
        for (int mi = 0; mi < 2; mi++)
            #pragma unroll
            for (int ni = 0; ni < 2; ni++) {
                acc[mi][ni] = __builtin_amdgcn_mfma_f32_16x16x32_bf16(
                    fAh[mi], fBh[ni], acc[mi][ni], 0, 0, 0);
                acc[mi][ni] = __builtin_amdgcn_mfma_f32_16x16x32_bf16(
                    fAh[mi], fBl[ni], acc[mi][ni], 0, 0, 0);
                acc[mi][ni] = __builtin_amdgcn_mfma_f32_16x16x32_bf16(
                    fAl[mi], fBh[ni], acc[mi][ni], 0, 0, 0);
            }
    }

    #pragma unroll
    for (int mi = 0; mi < 2; mi++) {
        #pragma unroll
        for (int ni = 0; ni < 2; ni++) {
            int r0 = m0 + wm * 32 + mi * 16 + (lane >> 4) * 4;
            int c  = n0 + wn * 32 + ni * 16 + (lane & 15);
            #pragma unroll
            for (int j = 0; j < 4; j++) {
                float v = acc[mi][ni][j];
                if (EP == EP_GELU) {
                    v = fgelu(v + bias[c]);
                } else if (EP == EP_BIAS_ADD) {
                    v += bias[c];
                    v += add[(size_t)(r0 + j) * ldadd + c];
                }
                C[(size_t)(r0 + j) * ldc + c] = v;
            }
        }
    }
}

// ---------------------------------------------------------------------------
// Tiled fp32 GEMM (64x64x32, 4x4 micro-tile) — used for Wdt (K=32) only.
// ---------------------------------------------------------------------------
template<int EP>
__global__ __launch_bounds__(256) void gemm_nt(
        const float* __restrict__ A, int lda,
        const float* __restrict__ W,
        float* __restrict__ C, int ldc,
        const float* __restrict__ bias,
        const float* __restrict__ add, int ldadd,
        int M, int N, int K) {
    __shared__ float As[32][68];
    __shared__ float Bs[32][68];
    int tid = threadIdx.x;
    int tx = tid & 15, ty = tid >> 4;
    int m0 = blockIdx.y * 64, n0 = blockIdx.x * 64;
    int arow = tid >> 3;
    int acol = (tid & 7) * 4;
    float acc[4][4] = {};

    for (int k0 = 0; k0 < K; k0 += 32) {
        float4 a0 = *(const float4*)&A[(size_t)(m0 + arow) * lda + k0 + acol];
        float4 a1 = *(const float4*)&A[(size_t)(m0 + arow + 32) * lda + k0 + acol];
        float4 w0 = *(const float4*)&W[(size_t)(n0 + arow) * K + k0 + acol];
        float4 w1 = *(const float4*)&W[(size_t)(n0 + arow + 32) * K + k0 + acol];
        __syncthreads();
        As[acol + 0][arow] = a0.x; As[acol + 1][arow] = a0.y;
        As[acol + 2][arow] = a0.z; As[acol + 3][arow] = a0.w;
        As[acol + 0][arow + 32] = a1.x; As[acol + 1][arow + 32] = a1.y;
        As[acol + 2][arow + 32] = a1.z; As[acol + 3][arow + 32] = a1.w;
        Bs[acol + 0][arow] = w0.x; Bs[acol + 1][arow] = w0.y;
        Bs[acol + 2][arow] = w0.z; Bs[acol + 3][arow] = w0.w;
        Bs[acol + 0][arow + 32] = w1.x; Bs[acol + 1][arow + 32] = w1.y;
        Bs[acol + 2][arow + 32] = w1.z; Bs[acol + 3][arow + 32] = w1.w;
        __syncthreads();
        #pragma unroll
        for (int kk = 0; kk < 32; kk++) {
            float av[4], bv[4];
            *(float4*)&av[0] = *(const float4*)&As[kk][ty * 4];
            *(float4*)&bv[0] = *(const float4*)&Bs[kk][tx * 4];
            #pragma unroll
            for (int i = 0; i < 4; i++)
                #pragma unroll
                for (int j = 0; j < 4; j++)
                    acc[i][j] = fmaf(av[i], bv[j], acc[i][j]);
        }
    }

    int mbase = m0 + ty * 4, nbase = n0 + tx * 4;
    #pragma unroll
    for (int i = 0; i < 4; i++) {
        float vv[4];
        #pragma unroll
        for (int j = 0; j < 4; j++) {
            float v = acc[i][j];
            if (EP == EP_SOFTPLUS) {
                v = fsoftplus(v + bias[nbase + j]);
            } else if (EP == EP_GELU) {
                v = fgelu(v + bias[nbase + j]);
            } else if (EP == EP_BIAS_ADD) {
                v += bias[nbase + j];
                v += add[(size_t)(mbase + i) * ldadd + nbase + j];
            }
            vv[j] = v;
        }
        *(float4*)&C[(size_t)(mbase + i) * ldc + nbase] =
            make_float4(vv[0], vv[1], vv[2], vv[3]);
    }
}

// ---------------------------------------------------------------------------
// Split-K GEMM for the Wx projection: M=2304, N=64, K=1024, 4 K-slices.
// ---------------------------------------------------------------------------
__global__ __launch_bounds__(256) void gemm_wx_splitk(
        const float* __restrict__ A,      // [TOK][1024]
        const float* __restrict__ W,      // [64][1024]
        float* __restrict__ Cpart) {      // [4][TOK][64]
    __shared__ float As[32][68];
    __shared__ float Bs[32][68];
    int tid = threadIdx.x;
    int tx = tid & 15, ty = tid >> 4;
    int m0 = blockIdx.y * 64;
    int z = blockIdx.z;
    const float* Az = A + z * 256;
    const float* Wz = W + z * 256;
    int arow = tid >> 3;
    int acol = (tid & 7) * 4;
    float acc[4][4] = {};

    for (int k0 = 0; k0 < 256; k0 += 32) {
        float4 a0 = *(const float4*)&Az[(size_t)(m0 + arow) * 1024 + k0 + acol];
        float4 a1 = *(const float4*)&Az[(size_t)(m0 + arow + 32) * 1024 + k0 + acol];
        float4 w0 = *(const float4*)&Wz[(size_t)(arow) * 1024 + k0 + acol];
        float4 w1 = *(const float4*)&Wz[(size_t)(arow + 32) * 1024 + k0 + acol];
        __syncthreads();
        As[acol + 0][arow] = a0.x; As[acol + 1][arow] = a0.y;
        As[acol + 2][arow] = a0.z; As[acol + 3][arow] = a0.w;
        As[acol + 0][arow + 32] = a1.x; As[acol + 1][arow + 32] = a1.y;
        As[acol + 2][arow + 32] = a1.z; As[acol + 3][arow + 32] = a1.w;
        Bs[acol + 0][arow] = w0.x; Bs[acol + 1][arow] = w0.y;
        Bs[acol + 2][arow] = w0.z; Bs[acol + 3][arow] = w0.w;
        Bs[acol + 0][arow + 32] = w1.x; Bs[acol + 1][arow + 32] = w1.y;
        Bs[acol + 2][arow + 32] = w1.z; Bs[acol + 3][arow + 32] = w1.w;
        __syncthreads();
        #pragma unroll
        for (int kk = 0; kk < 32; kk++) {
            float av[4], bv[4];
            *(float4*)&av[0] = *(const float4*)&As[kk][ty * 4];
            *(float4*)&bv[0] = *(const float4*)&Bs[kk][tx * 4];
            #pragma unroll
            for (int i = 0; i < 4; i++)
                #pragma unroll
                for (int j = 0; j < 4; j++)
                    acc[i][j] = fmaf(av[i], bv[j], acc[i][j]);
        }
    }

    float* Cz = Cpart + (size_t)z * TOK * 64;
    int mbase = m0 + ty * 4, nbase = tx * 4;
    #pragma unroll
    for (int i = 0; i < 4; i++)
        *(float4*)&Cz[(size_t)(mbase + i) * 64 + nbase] =
            make_float4(acc[i][0], acc[i][1], acc[i][2], acc[i][3]);
}

__global__ __launch_bounds__(256) void reduce4_kernel(
        const float* __restrict__ Cpart, float* __restrict__ xd) {
    int i = blockIdx.x * 256 + threadIdx.x;
    const int M64 = TOK * 64;
    xd[i] = Cpart[i] + Cpart[M64 + i] + Cpart[2 * M64 + i] + Cpart[3 * M64 + i];
}

// ---------------------------------------------------------------------------
// Depthwise causal conv1d (k=4) + bias + SiLU. dir=1 = reverse in original
// sequence coordinates.
// ---------------------------------------------------------------------------
__global__ __launch_bounds__(256) void conv_silu_kernel(
        const float* __restrict__ xz, const float* __restrict__ w,
        const float* __restrict__ cb, float* __restrict__ out, int dir) {
    int idx = blockIdx.x * 256 + threadIdx.x;
    int c = idx & (D_INNER - 1);
    int t = idx >> 10;
    int b = t / NN, n = t % NN;
    const float* up = xz + (size_t)b * NN * (2 * D_INNER) + c;
    float4 wv = *(const float4*)&w[c * 4];
    float acc;
    if (dir == 0) {
        acc =                 up[(size_t)n * (2*D_INNER)] * wv.w;
        if (n >= 1) acc = fmaf(up[(size_t)(n-1) * (2*D_INNER)], wv.z, acc);
        if (n >= 2) acc = fmaf(up[(size_t)(n-2) * (2*D_INNER)], wv.y, acc);
        if (n >= 3) acc = fmaf(up[(size_t)(n-3) * (2*D_INNER)], wv.x, acc);
    } else {
        acc =                    up[(size_t)n * (2*D_INNER)] * wv.w;
        if (n+1 < NN) acc = fmaf(up[(size_t)(n+1) * (2*D_INNER)], wv.z, acc);
        if (n+2 < NN) acc = fmaf(up[(size_t)(n+2) * (2*D_INNER)], wv.y, acc);
        if (n+3 < NN) acc = fmaf(up[(size_t)(n+3) * (2*D_INNER)], wv.x, acc);
    }
    out[(size_t)t * D_INNER + c] = fsilu(acc + cb[c]);
}

// ---------------------------------------------------------------------------
// Selective scan, time-batched by 16. One wave: 4 d-channels x 16 states.
// dir=0: n=0..N-1; dir=1: n=N-1..0. y may alias u.
// ---------------------------------------------------------------------------
__global__ __launch_bounds__(256) void scan_kernel(
        const float* __restrict__ dt, const float* __restrict__ xdbl,
        const float* __restrict__ u, const float* __restrict__ xz,
        const float* __restrict__ Alog, const float* __restrict__ Dp,
        float* __restrict__ y, int dir) {
    int lane = threadIdx.x & 63;
    int wave = threadIdx.x >> 6;
    int w = blockIdx.x * 4 + wave;
    int s = lane & 15;
    int dl = lane >> 4;
    int b = w >> 8;
    int d = (w & 255) * 4 + dl;
    float A_ds = -fexp(Alog[d * D_STATE + s]);
    float Dd = Dp[d];
    float h = 0.f;
    const int UF = 16;
    for (int i0 = 0; i0 < NN; i0 += UF) {
        float dtv[UF], uv[UF], Bv[UF], Cv[UF];
        #pragma unroll
        for (int j = 0; j < UF; j++) {
            int i = i0 + j;
            int n = dir ? (NN - 1 - i) : i;
            size_t tt = (size_t)b * NN + n;
            dtv[j] = dt[tt * D_INNER + d];
            uv[j]  = u[tt * D_INNER + d];
            Bv[j]  = xdbl[tt * 64 + 32 + s];
            Cv[j]  = xdbl[tt * 64 + 48 + s];
        }
        float p[UF];
        #pragma unroll
        for (int j = 0; j < UF; j++) {
            float dA = fexp(dtv[j] * A_ds);
            h = fmaf(dA, h, dtv[j] * Bv[j] * uv[j]);
            p[j] = h * Cv[j];
        }
        #pragma unroll
        for (int j = 0; j < UF; j++) {
            p[j] += __shfl_xor(p[j], 1);
            p[j] += __shfl_xor(p[j], 2);
            p[j] += __shfl_xor(p[j], 4);
            p[j] += __shfl_xor(p[j], 8);
        }
        if (s == 0) {
            #pragma unroll
            for (int j = 0; j < UF; j++) {
                int i = i0 + j;
                int n = dir ? (NN - 1 - i) : i;
                size_t tt = (size_t)b * NN + n;
                float zv = xz[tt * (2 * D_INNER) + D_INNER + d];
                float yv = p[j] + uv[j] * Dd;
                yv *= fsilu(zv);
                y[tt * D_INNER + d] = yv;
            }
        }
    }
}

// ---------------------------------------------------------------------------
extern "C" void kernel_launch(void* const* d_in, const int* in_sizes, int n_in,
                              void* d_out, int out_size, void* d_ws, size_t ws_size,
                              hipStream_t stream) {
    const float* x       = (const float*)d_in[0];
    const float* g1      = (const float*)d_in[1];
    const float* b1      = (const float*)d_in[2];
    const float* g2      = (const float*)d_in[3];
    const float* b2      = (const float*)d_in[4];
    const float* merge_W = (const float*)d_in[5];
    const float* merge_b = (const float*)d_in[6];
    const float* ffn_W1  = (const float*)d_in[7];
    const float* ffn_b1  = (const float*)d_in[8];
    const float* ffn_W2  = (const float*)d_in[9];
    const float* ffn_b2  = (const float*)d_in[10];
    const float* Win[2]   = {(const float*)d_in[11], (const float*)d_in[20]};
    const float* convw[2] = {(const float*)d_in[12], (const float*)d_in[21]};
    const float* convb[2] = {(const float*)d_in[13], (const float*)d_in[22]};
    const float* Wx[2]    = {(const float*)d_in[14], (const float*)d_in[23]};
    const float* Wdt[2]   = {(const float*)d_in[15], (const float*)d_in[24]};
    const float* bdt[2]   = {(const float*)d_in[16], (const float*)d_in[25]};
    const float* Alog[2]  = {(const float*)d_in[17], (const float*)d_in[26]};
    const float* Dp[2]    = {(const float*)d_in[18], (const float*)d_in[27]};
    const float* Wout[2]  = {(const float*)d_in[19], (const float*)d_in[28]};
    float* out = (float*)d_out;

    // workspace layout (floats) — both directions share one buffer set
    float* ws = (float*)d_ws;
    const size_t T = TOK;
    float* xn  = ws;                       // T*512   (reused as xn2 later)
    float* xz  = xn  + T * 512;            // T*2048  (reused as FFN hidden)
    float* uc  = xz  + T * 2048;           // T*1024  (y aliases)
    float* xd  = uc  + T * 1024;           // T*64
    float* dt  = xd  + T * 64;             // T*1024
    float* xfb = dt  + T * 1024;           // T*1024  (concat xf|xb)
    float* x2  = xfb + T * 1024;           // T*512
    // xd4 (split-K partials) aliases x2: last use step 4 p=1, x2 first
    // written step 8.
    float* xd4 = x2;

    // 1. LN1
    ln_kernel<<<TOK, 64, 0, stream>>>(x, g1, b1, xn);

    for (int p = 0; p < 2; p++) {
        // 2. xz = xn @ Win^T   (T x 2048)  [MFMA]
        gemm_mfma<EP_NONE><<<dim3(2048/64, TOK/64), 256, 0, stream>>>(
            xn, 512, Win[p], xz, 2048, nullptr, nullptr, 0, 2048, 512);
        // 3. conv + silu -> uc
        conv_silu_kernel<<<TOK * D_INNER / 256, 256, 0, stream>>>(
            xz, convw[p], convb[p], uc, p);
        // 4. x_dbl = uc @ Wx^T  (T x 64), split-K x4 + reduce
        gemm_wx_splitk<<<dim3(1, TOK/64, 4), 256, 0, stream>>>(uc, Wx[p], xd4);
        reduce4_kernel<<<TOK * 64 / 256, 256, 0, stream>>>(xd4, xd);
        // 5. dt = softplus(dt_raw @ Wdt^T + bdt)  (T x 1024)
        gemm_nt<EP_SOFTPLUS><<<dim3(1024/64, TOK/64), 256, 0, stream>>>(
            xd, 64, Wdt[p], dt, 1024, bdt[p], nullptr, 0, TOK, 1024, 32);
        // 6. selective scan (+ u*D, * silu(z)); y aliases uc
        scan_kernel<<<256, 256, 0, stream>>>(
            dt, xd, uc, xz, Alog[p], Dp[p], uc, p);
        // 7. xf/xb = y @ Wout^T  (T x 512) -> halves of xfb  [MFMA]
        gemm_mfma<EP_NONE><<<dim3(512/64, TOK/64), 256, 0, stream>>>(
            uc, 1024, Wout[p], xfb + p * 512, 1024, nullptr, nullptr, 0, 512, 1024);
    }

    // 8. x2 = x + [xf|xb] @ merge_W^T + merge_b  [MFMA]
    gemm_mfma<EP_BIAS_ADD><<<dim3(512/64, TOK/64), 256, 0, stream>>>(
        xfb, 1024, merge_W, x2, 512, merge_b, x, 512, 512, 1024);

    // 9. LN2 (xn buffer reused)
    ln_kernel<<<TOK, 64, 0, stream>>>(x2, g2, b2, xn);

    // 10. h = gelu(xn2 @ ffn_W1^T + b1)   (T x 2048), reuse xz  [MFMA]
    gemm_mfma<EP_GELU><<<dim3(2048/64, TOK/64), 256, 0, stream>>>(
        xn, 512, ffn_W1, xz, 2048, ffn_b1, nullptr, 0, 2048, 512);

    // 11. out = x2 + h @ ffn_W2^T + b2  [MFMA]
    gemm_mfma<EP_BIAS_ADD><<<dim3(512/64, TOK/64), 256, 0, stream>>>(
        xz, 2048, ffn_W2, out, 512, ffn_b2, x2, 512, 512, 2048);
}

// Round 12
// 594.994 us; speedup vs baseline: 1.8439x; 1.1281x over previous
//
#include <hip/hip_runtime.h>
#include <hip/hip_bf16.h>
#include <math.h>

// Problem constants
#define D_MODEL 512
#define D_STATE 16
#define D_CONV  4
#define D_INNER 1024
#define DT_RANK 32
#define BB      4
#define NN      576
#define TOK     (BB*NN)   // 2304 tokens
#define NCHUNK  6
#define CLEN    (NN/NCHUNK)   // 96

// Fast device math: native v_exp_f32/v_log_f32 (~2 ulp; passing absmax 0.0156)
__device__ __forceinline__ float fexp(float x)  { return __expf(x); }
__device__ __forceinline__ float fsilu(float x) { return x / (1.f + __expf(-x)); }
__device__ __forceinline__ float fsoftplus(float x) {
    return fmaxf(x, 0.f) + __logf(1.f + __expf(-fabsf(x)));
}
__device__ __forceinline__ float fgelu(float u) {
    float a = 0.7978845608028654f * (u + 0.044715f * u * u * u);
    float t = 1.f - 2.f / (1.f + __expf(2.f * a));   // tanh(a)
    return 0.5f * u * (1.f + t);
}

// ---------------------------------------------------------------------------
// LayerNorm: one wave per token of 512 elems
// ---------------------------------------------------------------------------
__global__ __launch_bounds__(64) void ln_kernel(const float* __restrict__ x,
                                                const float* __restrict__ g,
                                                const float* __restrict__ b,
                                                float* __restrict__ o) {
    int t = blockIdx.x;
    int lane = threadIdx.x;
    const float* xr = x + (size_t)t * D_MODEL;
    float4 v0 = ((const float4*)xr)[lane];
    float4 v1 = ((const float4*)xr)[64 + lane];
    float s = v0.x + v0.y + v0.z + v0.w + v1.x + v1.y + v1.z + v1.w;
    #pragma unroll
    for (int m = 32; m; m >>= 1) s += __shfl_xor(s, m);
    float mean = s * (1.0f / D_MODEL);
    float dx[8] = {v0.x-mean, v0.y-mean, v0.z-mean, v0.w-mean,
                   v1.x-mean, v1.y-mean, v1.z-mean, v1.w-mean};
    float q = 0.f;
    #pragma unroll
    for (int i = 0; i < 8; i++) q += dx[i]*dx[i];
    #pragma unroll
    for (int m = 32; m; m >>= 1) q += __shfl_xor(q, m);
    float rstd = rsqrtf(q * (1.0f / D_MODEL) + 1e-5f);
    float4 g0 = ((const float4*)g)[lane], g1 = ((const float4*)g)[64 + lane];
    float4 b0 = ((const float4*)b)[lane], b1 = ((const float4*)b)[64 + lane];
    float4 o0, o1;
    o0.x = dx[0]*rstd*g0.x + b0.x; o0.y = dx[1]*rstd*g0.y + b0.y;
    o0.z = dx[2]*rstd*g0.z + b0.z; o0.w = dx[3]*rstd*g0.w + b0.w;
    o1.x = dx[4]*rstd*g1.x + b1.x; o1.y = dx[5]*rstd*g1.y + b1.y;
    o1.z = dx[6]*rstd*g1.z + b1.z; o1.w = dx[7]*rstd*g1.w + b1.w;
    float* orow = o + (size_t)t * D_MODEL;
    ((float4*)orow)[lane] = o0;
    ((float4*)orow)[64 + lane] = o1;
}

#define EP_NONE     0
#define EP_SOFTPLUS 1
#define EP_GELU     2
#define EP_BIAS_ADD 3

// ---------------------------------------------------------------------------
// MFMA bf16x3-split GEMM (verified r10: 1097->671us, absmax unchanged).
// C[m,n] = sum_k A[m,k]*W[n,k]; A,W split hi+lo bf16; 3 MFMA per tile.
// ---------------------------------------------------------------------------
typedef __attribute__((ext_vector_type(8))) short bf16x8;
typedef __attribute__((ext_vector_type(4))) float f32x4;

__device__ __forceinline__ void split8(float4 q0, float4 q1,
                                       uint4 &hi, uint4 &lo) {
    float f[8] = {q0.x, q0.y, q0.z, q0.w, q1.x, q1.y, q1.z, q1.w};
    unsigned hb[8], lb[8];
    #pragma unroll
    for (int i = 0; i < 8; i++) {
        unsigned u = __float_as_uint(f[i]);
        unsigned r = (u + 0x7FFFu + ((u >> 16) & 1u)) >> 16;  // bf16 RNE
        hb[i] = r & 0xFFFFu;
        float lf = f[i] - __uint_as_float(r << 16);
        unsigned ul = __float_as_uint(lf);
        lb[i] = ((ul + 0x7FFFu + ((ul >> 16) & 1u)) >> 16) & 0xFFFFu;
    }
    hi = make_uint4(hb[0]|(hb[1]<<16), hb[2]|(hb[3]<<16),
                    hb[4]|(hb[5]<<16), hb[6]|(hb[7]<<16));
    lo = make_uint4(lb[0]|(lb[1]<<16), lb[2]|(lb[3]<<16),
                    lb[4]|(lb[5]<<16), lb[6]|(lb[7]<<16));
}

template<int EP>
__global__ __launch_bounds__(256) void gemm_mfma(
        const float* __restrict__ A, int lda,
        const float* __restrict__ W,
        float* __restrict__ C, int ldc,
        const float* __restrict__ bias,
        const float* __restrict__ add, int ldadd,
        int N, int K) {
    __shared__ short AsH[64][40], AsL[64][40], BsH[64][40], BsL[64][40];
    int tid  = threadIdx.x;
    int lane = tid & 63;
    int wave = tid >> 6;
    int wm = wave >> 1, wn = wave & 1;
    int m0 = blockIdx.y * 64, n0 = blockIdx.x * 64;
    int srow = tid >> 2;            // 0..63 staging row
    int skb  = (tid & 3) * 8;       // k-offset 0,8,16,24

    f32x4 acc[2][2] = {};

    for (int k0 = 0; k0 < K; k0 += 32) {
        float4 a0 = *(const float4*)&A[(size_t)(m0 + srow) * lda + k0 + skb];
        float4 a1 = *(const float4*)&A[(size_t)(m0 + srow) * lda + k0 + skb + 4];
        float4 w0 = *(const float4*)&W[(size_t)(n0 + srow) * K + k0 + skb];
        float4 w1 = *(const float4*)&W[(size_t)(n0 + srow) * K + k0 + skb + 4];
        uint4 ah, al, bh, bl;
        split8(a0, a1, ah, al);
        split8(w0, w1, bh, bl);
        __syncthreads();            // previous tile fully consumed
        *(uint4*)&AsH[srow][skb] = ah;
        *(uint4*)&AsL[srow][skb] = al;
        *(uint4*)&BsH[srow][skb] = bh;
        *(uint4*)&BsL[srow][skb] = bl;
        __syncthreads();

        int hk = (lane >> 4) * 8;
        int rr = lane & 15;
        bf16x8 fAh[2], fAl[2], fBh[2], fBl[2];
        #pragma unroll
        for (int mi = 0; mi < 2; mi++) {
            int r = wm * 32 + mi * 16 + rr;
            fAh[mi] = *(const bf16x8*)&AsH[r][hk];
            fAl[mi] = *(const bf16x8*)&AsL[r][hk];
        }
        #pragma unroll
        for (int ni = 0; ni < 2; ni++) {
            int c = wn * 32 + ni * 16 + rr;
            fBh[ni] = *(const bf16x8*)&BsH[c][hk];
            fBl[ni] = *(const bf16x8*)&BsL[c][hk];
        }
        #pragma unroll
        for (int mi = 0; mi < 2; mi++)
            #pragma unroll
            for (int ni = 0; ni < 2; ni++) {
                acc[mi][ni] = __builtin_amdgcn_mfma_f32_16x16x32_bf16(
                    fAh[mi], fBh[ni], acc[mi][ni], 0, 0, 0);
                acc[mi][ni] = __builtin_amdgcn_mfma_f32_16x16x32_bf16(
                    fAh[mi], fBl[ni], acc[mi][ni], 0, 0, 0);
                acc[mi][ni] = __builtin_amdgcn_mfma_f32_16x16x32_bf16(
                    fAl[mi], fBh[ni], acc[mi][ni], 0, 0, 0);
            }
    }

    #pragma unroll
    for (int mi = 0; mi < 2; mi++) {
        #pragma unroll
        for (int ni = 0; ni < 2; ni++) {
            int r0 = m0 + wm * 32 + mi * 16 + (lane >> 4) * 4;
            int c  = n0 + wn * 32 + ni * 16 + (lane & 15);
            #pragma unroll
            for (int j = 0; j < 4; j++) {
                float v = acc[mi][ni][j];
                if (EP == EP_GELU) {
                    v = fgelu(v + bias[c]);
                } else if (EP == EP_BIAS_ADD) {
                    v += bias[c];
                    v += add[(size_t)(r0 + j) * ldadd + c];
                }
                C[(size_t)(r0 + j) * ldc + c] = v;
            }
        }
    }
}

// ---------------------------------------------------------------------------
// Tiled fp32 GEMM (64x64x32, 4x4 micro-tile) — used for Wdt (K=32) only.
// ---------------------------------------------------------------------------
template<int EP>
__global__ __launch_bounds__(256) void gemm_nt(
        const float* __restrict__ A, int lda,
        const float* __restrict__ W,
        float* __restrict__ C, int ldc,
        const float* __restrict__ bias,
        const float* __restrict__ add, int ldadd,
        int M, int N, int K) {
    __shared__ float As[32][68];
    __shared__ float Bs[32][68];
    int tid = threadIdx.x;
    int tx = tid & 15, ty = tid >> 4;
    int m0 = blockIdx.y * 64, n0 = blockIdx.x * 64;
    int arow = tid >> 3;
    int acol = (tid & 7) * 4;
    float acc[4][4] = {};

    for (int k0 = 0; k0 < K; k0 += 32) {
        float4 a0 = *(const float4*)&A[(size_t)(m0 + arow) * lda + k0 + acol];
        float4 a1 = *(const float4*)&A[(size_t)(m0 + arow + 32) * lda + k0 + acol];
        float4 w0 = *(const float4*)&W[(size_t)(n0 + arow) * K + k0 + acol];
        float4 w1 = *(const float4*)&W[(size_t)(n0 + arow + 32) * K + k0 + acol];
        __syncthreads();
        As[acol + 0][arow] = a0.x; As[acol + 1][arow] = a0.y;
        As[acol + 2][arow] = a0.z; As[acol + 3][arow] = a0.w;
        As[acol + 0][arow + 32] = a1.x; As[acol + 1][arow + 32] = a1.y;
        As[acol + 2][arow + 32] = a1.z; As[acol + 3][arow + 32] = a1.w;
        Bs[acol + 0][arow] = w0.x; Bs[acol + 1][arow] = w0.y;
        Bs[acol + 2][arow] = w0.z; Bs[acol + 3][arow] = w0.w;
        Bs[acol + 0][arow + 32] = w1.x; Bs[acol + 1][arow + 32] = w1.y;
        Bs[acol + 2][arow + 32] = w1.z; Bs[acol + 3][arow + 32] = w1.w;
        __syncthreads();
        #pragma unroll
        for (int kk = 0; kk < 32; kk++) {
            float av[4], bv[4];
            *(float4*)&av[0] = *(const float4*)&As[kk][ty * 4];
            *(float4*)&bv[0] = *(const float4*)&Bs[kk][tx * 4];
            #pragma unroll
            for (int i = 0; i < 4; i++)
                #pragma unroll
                for (int j = 0; j < 4; j++)
                    acc[i][j] = fmaf(av[i], bv[j], acc[i][j]);
        }
    }

    int mbase = m0 + ty * 4, nbase = n0 + tx * 4;
    #pragma unroll
    for (int i = 0; i < 4; i++) {
        float vv[4];
        #pragma unroll
        for (int j = 0; j < 4; j++) {
            float v = acc[i][j];
            if (EP == EP_SOFTPLUS) {
                v = fsoftplus(v + bias[nbase + j]);
            } else if (EP == EP_GELU) {
                v = fgelu(v + bias[nbase + j]);
            } else if (EP == EP_BIAS_ADD) {
                v += bias[nbase + j];
                v += add[(size_t)(mbase + i) * ldadd + nbase + j];
            }
            vv[j] = v;
        }
        *(float4*)&C[(size_t)(mbase + i) * ldc + nbase] =
            make_float4(vv[0], vv[1], vv[2], vv[3]);
    }
}

// ---------------------------------------------------------------------------
// Split-K GEMM for the Wx projection: M=2304, N=64, K=1024, 4 K-slices.
// ---------------------------------------------------------------------------
__global__ __launch_bounds__(256) void gemm_wx_splitk(
        const float* __restrict__ A,      // [TOK][1024]
        const float* __restrict__ W,      // [64][1024]
        float* __restrict__ Cpart) {      // [4][TOK][64]
    __shared__ float As[32][68];
    __shared__ float Bs[32][68];
    int tid = threadIdx.x;
    int tx = tid & 15, ty = tid >> 4;
    int m0 = blockIdx.y * 64;
    int z = blockIdx.z;
    const float* Az = A + z * 256;
    const float* Wz = W + z * 256;
    int arow = tid >> 3;
    int acol = (tid & 7) * 4;
    float acc[4][4] = {};

    for (int k0 = 0; k0 < 256; k0 += 32) {
        float4 a0 = *(const float4*)&Az[(size_t)(m0 + arow) * 1024 + k0 + acol];
        float4 a1 = *(const float4*)&Az[(size_t)(m0 + arow + 32) * 1024 + k0 + acol];
        float4 w0 = *(const float4*)&Wz[(size_t)(arow) * 1024 + k0 + acol];
        float4 w1 = *(const float4*)&Wz[(size_t)(arow + 32) * 1024 + k0 + acol];
        __syncthreads();
        As[acol + 0][arow] = a0.x; As[acol + 1][arow] = a0.y;
        As[acol + 2][arow] = a0.z; As[acol + 3][arow] = a0.w;
        As[acol + 0][arow + 32] = a1.x; As[acol + 1][arow + 32] = a1.y;
        As[acol + 2][arow + 32] = a1.z; As[acol + 3][arow + 32] = a1.w;
        Bs[acol + 0][arow] = w0.x; Bs[acol + 1][arow] = w0.y;
        Bs[acol + 2][arow] = w0.z; Bs[acol + 3][arow] = w0.w;
        Bs[acol + 0][arow + 32] = w1.x; Bs[acol + 1][arow + 32] = w1.y;
        Bs[acol + 2][arow + 32] = w1.z; Bs[acol + 3][arow + 32] = w1.w;
        __syncthreads();
        #pragma unroll
        for (int kk = 0; kk < 32; kk++) {
            float av[4], bv[4];
            *(float4*)&av[0] = *(const float4*)&As[kk][ty * 4];
            *(float4*)&bv[0] = *(const float4*)&Bs[kk][tx * 4];
            #pragma unroll
            for (int i = 0; i < 4; i++)
                #pragma unroll
                for (int j = 0; j < 4; j++)
                    acc[i][j] = fmaf(av[i], bv[j], acc[i][j]);
        }
    }

    float* Cz = Cpart + (size_t)z * TOK * 64;
    int mbase = m0 + ty * 4, nbase = tx * 4;
    #pragma unroll
    for (int i = 0; i < 4; i++)
        *(float4*)&Cz[(size_t)(mbase + i) * 64 + nbase] =
            make_float4(acc[i][0], acc[i][1], acc[i][2], acc[i][3]);
}

__global__ __launch_bounds__(256) void reduce4_kernel(
        const float* __restrict__ Cpart, float* __restrict__ xd) {
    int i = blockIdx.x * 256 + threadIdx.x;
    const int M64 = TOK * 64;
    xd[i] = Cpart[i] + Cpart[M64 + i] + Cpart[2 * M64 + i] + Cpart[3 * M64 + i];
}

// ---------------------------------------------------------------------------
// Depthwise causal conv1d (k=4) + bias + SiLU. dir=1 = reverse in original
// sequence coordinates.
// ---------------------------------------------------------------------------
__global__ __launch_bounds__(256) void conv_silu_kernel(
        const float* __restrict__ xz, const float* __restrict__ w,
        const float* __restrict__ cb, float* __restrict__ out, int dir) {
    int idx = blockIdx.x * 256 + threadIdx.x;
    int c = idx & (D_INNER - 1);
    int t = idx >> 10;
    int b = t / NN, n = t % NN;
    const float* up = xz + (size_t)b * NN * (2 * D_INNER) + c;
    float4 wv = *(const float4*)&w[c * 4];
    float acc;
    if (dir == 0) {
        acc =                 up[(size_t)n * (2*D_INNER)] * wv.w;
        if (n >= 1) acc = fmaf(up[(size_t)(n-1) * (2*D_INNER)], wv.z, acc);
        if (n >= 2) acc = fmaf(up[(size_t)(n-2) * (2*D_INNER)], wv.y, acc);
        if (n >= 3) acc = fmaf(up[(size_t)(n-3) * (2*D_INNER)], wv.x, acc);
    } else {
        acc =                    up[(size_t)n * (2*D_INNER)] * wv.w;
        if (n+1 < NN) acc = fmaf(up[(size_t)(n+1) * (2*D_INNER)], wv.z, acc);
        if (n+2 < NN) acc = fmaf(up[(size_t)(n+2) * (2*D_INNER)], wv.y, acc);
        if (n+3 < NN) acc = fmaf(up[(size_t)(n+3) * (2*D_INNER)], wv.x, acc);
    }
    out[(size_t)t * D_INNER + c] = fsilu(acc + cb[c]);
}

// ---------------------------------------------------------------------------
// Chunked selective scan, 3 phases. h_n = a_n h_{n-1} + q_n is linear, so
// chunk c's true init state is hin(c) = P(c-1)*hin(c-1) + hend(c-1) where
// P = prod(a) and hend = local scan from 0. 6 chunks x 96 steps -> 6144
// waves (6/SIMD) instead of 1024 (1/SIMD): latency finally overlaps.
// Wave mapping: w = blk*4+wave; dg=w&255, b=(w>>8)&3, c=w>>10.
// lane: s=lane&15, dl=lane>>4; d = dg*4+dl.
// Scratch layout (in dead x2 region): idx = ((c*4+b)*1024+d)*16+s.
// ---------------------------------------------------------------------------
__global__ __launch_bounds__(256) void scan_pass1(
        const float* __restrict__ dt, const float* __restrict__ xdbl,
        const float* __restrict__ u, const float* __restrict__ Alog,
        float* __restrict__ hend, float* __restrict__ prodA, int dir) {
    int lane = threadIdx.x & 63;
    int wave = threadIdx.x >> 6;
    int w = blockIdx.x * 4 + wave;        // 0..6143
    int s = lane & 15;
    int dl = lane >> 4;
    int dg = w & 255;
    int b  = (w >> 8) & 3;
    int c  = w >> 10;                      // 0..5
    int d = dg * 4 + dl;
    float A_ds = -fexp(Alog[d * D_STATE + s]);
    float h = 0.f, P = 1.f;
    const int UF = 16;
    for (int i0 = c * CLEN; i0 < (c + 1) * CLEN; i0 += UF) {
        float dtv[UF], uv[UF], Bv[UF];
        #pragma unroll
        for (int j = 0; j < UF; j++) {
            int i = i0 + j;
            int n = dir ? (NN - 1 - i) : i;
            size_t tt = (size_t)b * NN + n;
            dtv[j] = dt[tt * D_INNER + d];
            uv[j]  = u[tt * D_INNER + d];
            Bv[j]  = xdbl[tt * 64 + 32 + s];
        }
        #pragma unroll
        for (int j = 0; j < UF; j++) {
            float a = fexp(dtv[j] * A_ds);
            h = fmaf(a, h, dtv[j] * Bv[j] * uv[j]);
            P *= a;
        }
    }
    int idx = ((c * 4 + b) * 1024 + d) * 16 + s;
    hend[idx] = h;
    prodA[idx] = P;
}

// hin(0)=0; hin(c) = P(c-1)*hin(c-1) + hend(c-1). One thread per (b,d,s).
__global__ __launch_bounds__(256) void scan_combine(
        const float* __restrict__ hend, const float* __restrict__ prodA,
        float* __restrict__ hin) {
    int e = blockIdx.x * 256 + threadIdx.x;   // 0..65535
    float run = 0.f;
    #pragma unroll
    for (int c = 0; c < NCHUNK; c++) {
        hin[c * 65536 + e] = run;
        run = fmaf(prodA[c * 65536 + e], run, hend[c * 65536 + e]);
    }
}

__global__ __launch_bounds__(256) void scan_pass2(
        const float* __restrict__ dt, const float* __restrict__ xdbl,
        const float* __restrict__ u, const float* __restrict__ xz,
        const float* __restrict__ Alog, const float* __restrict__ Dp,
        const float* __restrict__ hin, float* __restrict__ y, int dir) {
    int lane = threadIdx.x & 63;
    int wave = threadIdx.x >> 6;
    int w = blockIdx.x * 4 + wave;        // 0..6143
    int s = lane & 15;
    int dl = lane >> 4;
    int dg = w & 255;
    int b  = (w >> 8) & 3;
    int c  = w >> 10;
    int d = dg * 4 + dl;
    float A_ds = -fexp(Alog[d * D_STATE + s]);
    float Dd = Dp[d];
    float h = hin[((c * 4 + b) * 1024 + d) * 16 + s];
    const int UF = 16;
    for (int i0 = c * CLEN; i0 < (c + 1) * CLEN; i0 += UF) {
        float dtv[UF], uv[UF], Bv[UF], Cv[UF];
        #pragma unroll
        for (int j = 0; j < UF; j++) {
            int i = i0 + j;
            int n = dir ? (NN - 1 - i) : i;
            size_t tt = (size_t)b * NN + n;
            dtv[j] = dt[tt * D_INNER + d];
            uv[j]  = u[tt * D_INNER + d];
            Bv[j]  = xdbl[tt * 64 + 32 + s];
            Cv[j]  = xdbl[tt * 64 + 48 + s];
        }
        float p[UF];
        #pragma unroll
        for (int j = 0; j < UF; j++) {
            float a = fexp(dtv[j] * A_ds);
            h = fmaf(a, h, dtv[j] * Bv[j] * uv[j]);
            p[j] = h * Cv[j];
        }
        #pragma unroll
        for (int j = 0; j < UF; j++) {
            p[j] += __shfl_xor(p[j], 1);
            p[j] += __shfl_xor(p[j], 2);
            p[j] += __shfl_xor(p[j], 4);
            p[j] += __shfl_xor(p[j], 8);
        }
        if (s == 0) {
            #pragma unroll
            for (int j = 0; j < UF; j++) {
                int i = i0 + j;
                int n = dir ? (NN - 1 - i) : i;
                size_t tt = (size_t)b * NN + n;
                float zv = xz[tt * (2 * D_INNER) + D_INNER + d];
                float yv = p[j] + uv[j] * Dd;
                yv *= fsilu(zv);
                y[tt * D_INNER + d] = yv;
            }
        }
    }
}

// ---------------------------------------------------------------------------
extern "C" void kernel_launch(void* const* d_in, const int* in_sizes, int n_in,
                              void* d_out, int out_size, void* d_ws, size_t ws_size,
                              hipStream_t stream) {
    const float* x       = (const float*)d_in[0];
    const float* g1      = (const float*)d_in[1];
    const float* b1      = (const float*)d_in[2];
    const float* g2      = (const float*)d_in[3];
    const float* b2      = (const float*)d_in[4];
    const float* merge_W = (const float*)d_in[5];
    const float* merge_b = (const float*)d_in[6];
    const float* ffn_W1  = (const float*)d_in[7];
    const float* ffn_b1  = (const float*)d_in[8];
    const float* ffn_W2  = (const float*)d_in[9];
    const float* ffn_b2  = (const float*)d_in[10];
    const float* Win[2]   = {(const float*)d_in[11], (const float*)d_in[20]};
    const float* convw[2] = {(const float*)d_in[12], (const float*)d_in[21]};
    const float* convb[2] = {(const float*)d_in[13], (const float*)d_in[22]};
    const float* Wx[2]    = {(const float*)d_in[14], (const float*)d_in[23]};
    const float* Wdt[2]   = {(const float*)d_in[15], (const float*)d_in[24]};
    const float* bdt[2]   = {(const float*)d_in[16], (const float*)d_in[25]};
    const float* Alog[2]  = {(const float*)d_in[17], (const float*)d_in[26]};
    const float* Dp[2]    = {(const float*)d_in[18], (const float*)d_in[27]};
    const float* Wout[2]  = {(const float*)d_in[19], (const float*)d_in[28]};
    float* out = (float*)d_out;

    // workspace layout (floats) — both directions share one buffer set
    float* ws = (float*)d_ws;
    const size_t T = TOK;
    float* xn  = ws;                       // T*512   (reused as xn2 later)
    float* xz  = xn  + T * 512;            // T*2048  (reused as FFN hidden)
    float* uc  = xz  + T * 2048;           // T*1024  (y aliases)
    float* xd  = uc  + T * 1024;           // T*64
    float* dt  = xd  + T * 64;             // T*1024
    float* xfb = dt  + T * 1024;           // T*1024  (concat xf|xb)
    float* x2  = xfb + T * 1024;           // T*512
    // x2 region (T*512 = 1179648 floats) triple-aliased, timeline-disjoint:
    //  - xd4 split-K partials (steps 4-5 of each p)
    //  - scan scratch hend|prodA|hin (step 6 of each p): 3 x 6*65536 floats
    //    = 1179648 exactly
    //  - x2 proper (step 8 onward)
    float* xd4   = x2;
    float* hendb = x2;
    float* prodb = x2 + (size_t)NCHUNK * 65536;
    float* hinb  = x2 + (size_t)2 * NCHUNK * 65536;

    // 1. LN1
    ln_kernel<<<TOK, 64, 0, stream>>>(x, g1, b1, xn);

    for (int p = 0; p < 2; p++) {
        // 2. xz = xn @ Win^T   (T x 2048)  [MFMA]
        gemm_mfma<EP_NONE><<<dim3(2048/64, TOK/64), 256, 0, stream>>>(
            xn, 512, Win[p], xz, 2048, nullptr, nullptr, 0, 2048, 512);
        // 3. conv + silu -> uc
        conv_silu_kernel<<<TOK * D_INNER / 256, 256, 0, stream>>>(
            xz, convw[p], convb[p], uc, p);
        // 4. x_dbl = uc @ Wx^T  (T x 64), split-K x4 + reduce
        gemm_wx_splitk<<<dim3(1, TOK/64, 4), 256, 0, stream>>>(uc, Wx[p], xd4);
        reduce4_kernel<<<TOK * 64 / 256, 256, 0, stream>>>(xd4, xd);
        // 5. dt = softplus(dt_raw @ Wdt^T + bdt)  (T x 1024)
        gemm_nt<EP_SOFTPLUS><<<dim3(1024/64, TOK/64), 256, 0, stream>>>(
            xd, 64, Wdt[p], dt, 1024, bdt[p], nullptr, 0, TOK, 1024, 32);
        // 6. chunked selective scan; y aliases uc (chunk-disjoint writes)
        scan_pass1<<<NCHUNK * 256, 256, 0, stream>>>(
            dt, xd, uc, Alog[p], hendb, prodb, p);
        scan_combine<<<256, 256, 0, stream>>>(hendb, prodb, hinb);
        scan_pass2<<<NCHUNK * 256, 256, 0, stream>>>(
            dt, xd, uc, xz, Alog[p], Dp[p], hinb, uc, p);
        // 7. xf/xb = y @ Wout^T  (T x 512) -> halves of xfb  [MFMA]
        gemm_mfma<EP_NONE><<<dim3(512/64, TOK/64), 256, 0, stream>>>(
            uc, 1024, Wout[p], xfb + p * 512, 1024, nullptr, nullptr, 0, 512, 1024);
    }

    // 8. x2 = x + [xf|xb] @ merge_W^T + merge_b  [MFMA]
    gemm_mfma<EP_BIAS_ADD><<<dim3(512/64, TOK/64), 256, 0, stream>>>(
        xfb, 1024, merge_W, x2, 512, merge_b, x, 512, 512, 1024);

    // 9. LN2 (xn buffer reused)
    ln_kernel<<<TOK, 64, 0, stream>>>(x2, g2, b2, xn);

    // 10. h = gelu(xn2 @ ffn_W1^T + b1)   (T x 2048), reuse xz  [MFMA]
    gemm_mfma<EP_GELU><<<dim3(2048/64, TOK/64), 256, 0, stream>>>(
        xn, 512, ffn_W1, xz, 2048, ffn_b1, nullptr, 0, 2048, 512);

    // 11. out = x2 + h @ ffn_W2^T + b2  [MFMA]
    gemm_mfma<EP_BIAS_ADD><<<dim3(512/64, TOK/64), 256, 0, stream>>>(
        xz, 2048, ffn_W2, out, 512, ffn_b2, x2, 512, 512, 2048);
}

// Round 13
// 553.996 us; speedup vs baseline: 1.9803x; 1.0740x over previous
//
#include <hip/hip_runtime.h>
#include <hip/hip_bf16.h>
#include <math.h>

// Problem constants
#define D_MODEL 512
#define D_STATE 16
#define D_CONV  4
#define D_INNER 1024
#define DT_RANK 32
#define BB      4
#define NN      576
#define TOK     (BB*NN)   // 2304 tokens
#define NCHUNK  6
#define CLEN    (NN/NCHUNK)   // 96

// Fast device math: native v_exp_f32/v_log_f32 (~2 ulp; passing absmax 0.0156)
__device__ __forceinline__ float fexp(float x)  { return __expf(x); }
__device__ __forceinline__ float fsilu(float x) { return x / (1.f + __expf(-x)); }
__device__ __forceinline__ float fsoftplus(float x) {
    return fmaxf(x, 0.f) + __logf(1.f + __expf(-fabsf(x)));
}
__device__ __forceinline__ float fgelu(float u) {
    float a = 0.7978845608028654f * (u + 0.044715f * u * u * u);
    float t = 1.f - 2.f / (1.f + __expf(2.f * a));   // tanh(a)
    return 0.5f * u * (1.f + t);
}

// ---------------------------------------------------------------------------
// LayerNorm: one wave per token of 512 elems
// ---------------------------------------------------------------------------
__global__ __launch_bounds__(64) void ln_kernel(const float* __restrict__ x,
                                                const float* __restrict__ g,
                                                const float* __restrict__ b,
                                                float* __restrict__ o) {
    int t = blockIdx.x;
    int lane = threadIdx.x;
    const float* xr = x + (size_t)t * D_MODEL;
    float4 v0 = ((const float4*)xr)[lane];
    float4 v1 = ((const float4*)xr)[64 + lane];
    float s = v0.x + v0.y + v0.z + v0.w + v1.x + v1.y + v1.z + v1.w;
    #pragma unroll
    for (int m = 32; m; m >>= 1) s += __shfl_xor(s, m);
    float mean = s * (1.0f / D_MODEL);
    float dx[8] = {v0.x-mean, v0.y-mean, v0.z-mean, v0.w-mean,
                   v1.x-mean, v1.y-mean, v1.z-mean, v1.w-mean};
    float q = 0.f;
    #pragma unroll
    for (int i = 0; i < 8; i++) q += dx[i]*dx[i];
    #pragma unroll
    for (int m = 32; m; m >>= 1) q += __shfl_xor(q, m);
    float rstd = rsqrtf(q * (1.0f / D_MODEL) + 1e-5f);
    float4 g0 = ((const float4*)g)[lane], g1 = ((const float4*)g)[64 + lane];
    float4 b0 = ((const float4*)b)[lane], b1 = ((const float4*)b)[64 + lane];
    float4 o0, o1;
    o0.x = dx[0]*rstd*g0.x + b0.x; o0.y = dx[1]*rstd*g0.y + b0.y;
    o0.z = dx[2]*rstd*g0.z + b0.z; o0.w = dx[3]*rstd*g0.w + b0.w;
    o1.x = dx[4]*rstd*g1.x + b1.x; o1.y = dx[5]*rstd*g1.y + b1.y;
    o1.z = dx[6]*rstd*g1.z + b1.z; o1.w = dx[7]*rstd*g1.w + b1.w;
    float* orow = o + (size_t)t * D_MODEL;
    ((float4*)orow)[lane] = o0;
    ((float4*)orow)[64 + lane] = o1;
}

#define EP_NONE     0
#define EP_SOFTPLUS 1
#define EP_GELU     2
#define EP_BIAS_ADD 3

// ---------------------------------------------------------------------------
// MFMA bf16x3-split GEMM. r12 profile: 80us/dispatch, MfmaUtil 6.5%,
// 4.7M LDS bank conflicts, nothing saturated -> latency+conflict bound.
// r13 fixes: (1) LDS row pad 40->44 shorts (88B=22 banks; 22r%32 distinct
// for r=0..15 -> 2-way max = free), (2) register prefetch of next K-tile
// issued before the MFMA cluster (global latency hides under compute),
// (3) truncation split (AND/SUB/SHIFT, ~3x fewer VALU than RNE; error
// ~2^-14 rel, absmax budget 0.0156).
// ---------------------------------------------------------------------------
typedef __attribute__((ext_vector_type(8))) short bf16x8;
typedef __attribute__((ext_vector_type(4))) float f32x4;

__device__ __forceinline__ void split8t(float4 q0, float4 q1,
                                        uint4 &hi, uint4 &lo) {
    float f[8] = {q0.x, q0.y, q0.z, q0.w, q1.x, q1.y, q1.z, q1.w};
    unsigned hu[8], lu[8];
    #pragma unroll
    for (int i = 0; i < 8; i++) {
        unsigned u = __float_as_uint(f[i]);
        hu[i] = u & 0xFFFF0000u;                       // bf16 hi (truncate)
        float lf = f[i] - __uint_as_float(hu[i]);      // exact residual
        lu[i] = __float_as_uint(lf) & 0xFFFF0000u;     // bf16 lo (truncate)
    }
    hi = make_uint4((hu[0] >> 16) | hu[1], (hu[2] >> 16) | hu[3],
                    (hu[4] >> 16) | hu[5], (hu[6] >> 16) | hu[7]);
    lo = make_uint4((lu[0] >> 16) | lu[1], (lu[2] >> 16) | lu[3],
                    (lu[4] >> 16) | lu[5], (lu[6] >> 16) | lu[7]);
}

#define LDSW 44   // LDS row stride in shorts (88 B = 22 banks, conflict-free)

template<int EP>
__global__ __launch_bounds__(256) void gemm_mfma(
        const float* __restrict__ A, int lda,
        const float* __restrict__ W,
        float* __restrict__ C, int ldc,
        const float* __restrict__ bias,
        const float* __restrict__ add, int ldadd,
        int N, int K) {
    __shared__ short AsH[64][LDSW], AsL[64][LDSW], BsH[64][LDSW], BsL[64][LDSW];
    int tid  = threadIdx.x;
    int lane = tid & 63;
    int wave = tid >> 6;
    int wm = wave >> 1, wn = wave & 1;
    int m0 = blockIdx.y * 64, n0 = blockIdx.x * 64;
    int srow = tid >> 2;            // 0..63 staging row
    int skb  = (tid & 3) * 8;       // k-offset 0,8,16,24

    f32x4 acc[2][2] = {};

    const float* pA = &A[(size_t)(m0 + srow) * lda + skb];
    const float* pW = &W[(size_t)(n0 + srow) * K + skb];
    float4 a0 = *(const float4*)(pA);
    float4 a1 = *(const float4*)(pA + 4);
    float4 w0 = *(const float4*)(pW);
    float4 w1 = *(const float4*)(pW + 4);

    for (int k0 = 0; k0 < K; k0 += 32) {
        uint4 ah, al, bh, bl;
        split8t(a0, a1, ah, al);
        split8t(w0, w1, bh, bl);
        __syncthreads();            // previous tile fully consumed
        *(uint4*)&AsH[srow][skb] = ah;
        *(uint4*)&AsL[srow][skb] = al;
        *(uint4*)&BsH[srow][skb] = bh;
        *(uint4*)&BsL[srow][skb] = bl;
        __syncthreads();

        if (k0 + 32 < K) {          // issue next-tile loads BEFORE compute
            a0 = *(const float4*)(pA + k0 + 32);
            a1 = *(const float4*)(pA + k0 + 36);
            w0 = *(const float4*)(pW + k0 + 32);
            w1 = *(const float4*)(pW + k0 + 36);
        }

        int hk = (lane >> 4) * 8;
        int rr = lane & 15;
        bf16x8 fAh[2], fAl[2], fBh[2], fBl[2];
        #pragma unroll
        for (int mi = 0; mi < 2; mi++) {
            int r = wm * 32 + mi * 16 + rr;
            fAh[mi] = *(const bf16x8*)&AsH[r][hk];
            fAl[mi] = *(const bf16x8*)&AsL[r][hk];
        }
        #pragma unroll
        for (int ni = 0; ni < 2; ni++) {
            int c = wn * 32 + ni * 16 + rr;
            fBh[ni] = *(const bf16x8*)&BsH[c][hk];
            fBl[ni] = *(const bf16x8*)&BsL[c][hk];
        }
        #pragma unroll
        for (int mi = 0; mi < 2; mi++)
            #pragma unroll
            for (int ni = 0; ni < 2; ni++) {
                acc[mi][ni] = __builtin_amdgcn_mfma_f32_16x16x32_bf16(
                    fAh[mi], fBh[ni], acc[mi][ni], 0, 0, 0);
                acc[mi][ni] = __builtin_amdgcn_mfma_f32_16x16x32_bf16(
                    fAh[mi], fBl[ni], acc[mi][ni], 0, 0, 0);
                acc[mi][ni] = __builtin_amdgcn_mfma_f32_16x16x32_bf16(
                    fAl[mi], fBh[ni], acc[mi][ni], 0, 0, 0);
            }
    }

    #pragma unroll
    for (int mi = 0; mi < 2; mi++) {
        #pragma unroll
        for (int ni = 0; ni < 2; ni++) {
            int r0 = m0 + wm * 32 + mi * 16 + (lane >> 4) * 4;
            int c  = n0 + wn * 32 + ni * 16 + (lane & 15);
            #pragma unroll
            for (int j = 0; j < 4; j++) {
                float v = acc[mi][ni][j];
                if (EP == EP_GELU) {
                    v = fgelu(v + bias[c]);
                } else if (EP == EP_BIAS_ADD) {
                    v += bias[c];
                    v += add[(size_t)(r0 + j) * ldadd + c];
                }
                C[(size_t)(r0 + j) * ldc + c] = v;
            }
        }
    }
}

// ---------------------------------------------------------------------------
// Tiled fp32 GEMM (64x64x32, 4x4 micro-tile) — used for Wdt (K=32) only.
// ---------------------------------------------------------------------------
template<int EP>
__global__ __launch_bounds__(256) void gemm_nt(
        const float* __restrict__ A, int lda,
        const float* __restrict__ W,
        float* __restrict__ C, int ldc,
        const float* __restrict__ bias,
        const float* __restrict__ add, int ldadd,
        int M, int N, int K) {
    __shared__ float As[32][68];
    __shared__ float Bs[32][68];
    int tid = threadIdx.x;
    int tx = tid & 15, ty = tid >> 4;
    int m0 = blockIdx.y * 64, n0 = blockIdx.x * 64;
    int arow = tid >> 3;
    int acol = (tid & 7) * 4;
    float acc[4][4] = {};

    for (int k0 = 0; k0 < K; k0 += 32) {
        float4 a0 = *(const float4*)&A[(size_t)(m0 + arow) * lda + k0 + acol];
        float4 a1 = *(const float4*)&A[(size_t)(m0 + arow + 32) * lda + k0 + acol];
        float4 w0 = *(const float4*)&W[(size_t)(n0 + arow) * K + k0 + acol];
        float4 w1 = *(const float4*)&W[(size_t)(n0 + arow + 32) * K + k0 + acol];
        __syncthreads();
        As[acol + 0][arow] = a0.x; As[acol + 1][arow] = a0.y;
        As[acol + 2][arow] = a0.z; As[acol + 3][arow] = a0.w;
        As[acol + 0][arow + 32] = a1.x; As[acol + 1][arow + 32] = a1.y;
        As[acol + 2][arow + 32] = a1.z; As[acol + 3][arow + 32] = a1.w;
        Bs[acol + 0][arow] = w0.x; Bs[acol + 1][arow] = w0.y;
        Bs[acol + 2][arow] = w0.z; Bs[acol + 3][arow] = w0.w;
        Bs[acol + 0][arow + 32] = w1.x; Bs[acol + 1][arow + 32] = w1.y;
        Bs[acol + 2][arow + 32] = w1.z; Bs[acol + 3][arow + 32] = w1.w;
        __syncthreads();
        #pragma unroll
        for (int kk = 0; kk < 32; kk++) {
            float av[4], bv[4];
            *(float4*)&av[0] = *(const float4*)&As[kk][ty * 4];
            *(float4*)&bv[0] = *(const float4*)&Bs[kk][tx * 4];
            #pragma unroll
            for (int i = 0; i < 4; i++)
                #pragma unroll
                for (int j = 0; j < 4; j++)
                    acc[i][j] = fmaf(av[i], bv[j], acc[i][j]);
        }
    }

    int mbase = m0 + ty * 4, nbase = n0 + tx * 4;
    #pragma unroll
    for (int i = 0; i < 4; i++) {
        float vv[4];
        #pragma unroll
        for (int j = 0; j < 4; j++) {
            float v = acc[i][j];
            if (EP == EP_SOFTPLUS) {
                v = fsoftplus(v + bias[nbase + j]);
            } else if (EP == EP_GELU) {
                v = fgelu(v + bias[nbase + j]);
            } else if (EP == EP_BIAS_ADD) {
                v += bias[nbase + j];
                v += add[(size_t)(mbase + i) * ldadd + nbase + j];
            }
            vv[j] = v;
        }
        *(float4*)&C[(size_t)(mbase + i) * ldc + nbase] =
            make_float4(vv[0], vv[1], vv[2], vv[3]);
    }
}

// ---------------------------------------------------------------------------
// Split-K GEMM for the Wx projection: M=2304, N=64, K=1024, 4 K-slices.
// ---------------------------------------------------------------------------
__global__ __launch_bounds__(256) void gemm_wx_splitk(
        const float* __restrict__ A,      // [TOK][1024]
        const float* __restrict__ W,      // [64][1024]
        float* __restrict__ Cpart) {      // [4][TOK][64]
    __shared__ float As[32][68];
    __shared__ float Bs[32][68];
    int tid = threadIdx.x;
    int tx = tid & 15, ty = tid >> 4;
    int m0 = blockIdx.y * 64;
    int z = blockIdx.z;
    const float* Az = A + z * 256;
    const float* Wz = W + z * 256;
    int arow = tid >> 3;
    int acol = (tid & 7) * 4;
    float acc[4][4] = {};

    for (int k0 = 0; k0 < 256; k0 += 32) {
        float4 a0 = *(const float4*)&Az[(size_t)(m0 + arow) * 1024 + k0 + acol];
        float4 a1 = *(const float4*)&Az[(size_t)(m0 + arow + 32) * 1024 + k0 + acol];
        float4 w0 = *(const float4*)&Wz[(size_t)(arow) * 1024 + k0 + acol];
        float4 w1 = *(const float4*)&Wz[(size_t)(arow + 32) * 1024 + k0 + acol];
        __syncthreads();
        As[acol + 0][arow] = a0.x; As[acol + 1][arow] = a0.y;
        As[acol + 2][arow] = a0.z; As[acol + 3][arow] = a0.w;
        As[acol + 0][arow + 32] = a1.x; As[acol + 1][arow + 32] = a1.y;
        As[acol + 2][arow + 32] = a1.z; As[acol + 3][arow + 32] = a1.w;
        Bs[acol + 0][arow] = w0.x; Bs[acol + 1][arow] = w0.y;
        Bs[acol + 2][arow] = w0.z; Bs[acol + 3][arow] = w0.w;
        Bs[acol + 0][arow + 32] = w1.x; Bs[acol + 1][arow + 32] = w1.y;
        Bs[acol + 2][arow + 32] = w1.z; Bs[acol + 3][arow + 32] = w1.w;
        __syncthreads();
        #pragma unroll
        for (int kk = 0; kk < 32; kk++) {
            float av[4], bv[4];
            *(float4*)&av[0] = *(const float4*)&As[kk][ty * 4];
            *(float4*)&bv[0] = *(const float4*)&Bs[kk][tx * 4];
            #pragma unroll
            for (int i = 0; i < 4; i++)
                #pragma unroll
                for (int j = 0; j < 4; j++)
                    acc[i][j] = fmaf(av[i], bv[j], acc[i][j]);
        }
    }

    float* Cz = Cpart + (size_t)z * TOK * 64;
    int mbase = m0 + ty * 4, nbase = tx * 4;
    #pragma unroll
    for (int i = 0; i < 4; i++)
        *(float4*)&Cz[(size_t)(mbase + i) * 64 + nbase] =
            make_float4(acc[i][0], acc[i][1], acc[i][2], acc[i][3]);
}

__global__ __launch_bounds__(256) void reduce4_kernel(
        const float* __restrict__ Cpart, float* __restrict__ xd) {
    int i = blockIdx.x * 256 + threadIdx.x;
    const int M64 = TOK * 64;
    xd[i] = Cpart[i] + Cpart[M64 + i] + Cpart[2 * M64 + i] + Cpart[3 * M64 + i];
}

// ---------------------------------------------------------------------------
// Depthwise causal conv1d (k=4) + bias + SiLU. dir=1 = reverse in original
// sequence coordinates.
// ---------------------------------------------------------------------------
__global__ __launch_bounds__(256) void conv_silu_kernel(
        const float* __restrict__ xz, const float* __restrict__ w,
        const float* __restrict__ cb, float* __restrict__ out, int dir) {
    int idx = blockIdx.x * 256 + threadIdx.x;
    int c = idx & (D_INNER - 1);
    int t = idx >> 10;
    int b = t / NN, n = t % NN;
    const float* up = xz + (size_t)b * NN * (2 * D_INNER) + c;
    float4 wv = *(const float4*)&w[c * 4];
    float acc;
    if (dir == 0) {
        acc =                 up[(size_t)n * (2*D_INNER)] * wv.w;
        if (n >= 1) acc = fmaf(up[(size_t)(n-1) * (2*D_INNER)], wv.z, acc);
        if (n >= 2) acc = fmaf(up[(size_t)(n-2) * (2*D_INNER)], wv.y, acc);
        if (n >= 3) acc = fmaf(up[(size_t)(n-3) * (2*D_INNER)], wv.x, acc);
    } else {
        acc =                    up[(size_t)n * (2*D_INNER)] * wv.w;
        if (n+1 < NN) acc = fmaf(up[(size_t)(n+1) * (2*D_INNER)], wv.z, acc);
        if (n+2 < NN) acc = fmaf(up[(size_t)(n+2) * (2*D_INNER)], wv.y, acc);
        if (n+3 < NN) acc = fmaf(up[(size_t)(n+3) * (2*D_INNER)], wv.x, acc);
    }
    out[(size_t)t * D_INNER + c] = fsilu(acc + cb[c]);
}

// ---------------------------------------------------------------------------
// Chunked selective scan (verified r12: scan 225us -> ~150us total).
// hin(c) = P(c-1)*hin(c-1) + hend(c-1); 6 chunks x 96 steps.
// ---------------------------------------------------------------------------
__global__ __launch_bounds__(256) void scan_pass1(
        const float* __restrict__ dt, const float* __restrict__ xdbl,
        const float* __restrict__ u, const float* __restrict__ Alog,
        float* __restrict__ hend, float* __restrict__ prodA, int dir) {
    int lane = threadIdx.x & 63;
    int wave = threadIdx.x >> 6;
    int w = blockIdx.x * 4 + wave;        // 0..6143
    int s = lane & 15;
    int dl = lane >> 4;
    int dg = w & 255;
    int b  = (w >> 8) & 3;
    int c  = w >> 10;                      // 0..5
    int d = dg * 4 + dl;
    float A_ds = -fexp(Alog[d * D_STATE + s]);
    float h = 0.f, P = 1.f;
    const int UF = 16;
    for (int i0 = c * CLEN; i0 < (c + 1) * CLEN; i0 += UF) {
        float dtv[UF], uv[UF], Bv[UF];
        #pragma unroll
        for (int j = 0; j < UF; j++) {
            int i = i0 + j;
            int n = dir ? (NN - 1 - i) : i;
            size_t tt = (size_t)b * NN + n;
            dtv[j] = dt[tt * D_INNER + d];
            uv[j]  = u[tt * D_INNER + d];
            Bv[j]  = xdbl[tt * 64 + 32 + s];
        }
        #pragma unroll
        for (int j = 0; j < UF; j++) {
            float a = fexp(dtv[j] * A_ds);
            h = fmaf(a, h, dtv[j] * Bv[j] * uv[j]);
            P *= a;
        }
    }
    int idx = ((c * 4 + b) * 1024 + d) * 16 + s;
    hend[idx] = h;
    prodA[idx] = P;
}

// hin(0)=0; hin(c) = P(c-1)*hin(c-1) + hend(c-1). One thread per (b,d,s).
__global__ __launch_bounds__(256) void scan_combine(
        const float* __restrict__ hend, const float* __restrict__ prodA,
        float* __restrict__ hin) {
    int e = blockIdx.x * 256 + threadIdx.x;   // 0..65535
    float run = 0.f;
    #pragma unroll
    for (int c = 0; c < NCHUNK; c++) {
        hin[c * 65536 + e] = run;
        run = fmaf(prodA[c * 65536 + e], run, hend[c * 65536 + e]);
    }
}

__global__ __launch_bounds__(256) void scan_pass2(
        const float* __restrict__ dt, const float* __restrict__ xdbl,
        const float* __restrict__ u, const float* __restrict__ xz,
        const float* __restrict__ Alog, const float* __restrict__ Dp,
        const float* __restrict__ hin, float* __restrict__ y, int dir) {
    int lane = threadIdx.x & 63;
    int wave = threadIdx.x >> 6;
    int w = blockIdx.x * 4 + wave;        // 0..6143
    int s = lane & 15;
    int dl = lane >> 4;
    int dg = w & 255;
    int b  = (w >> 8) & 3;
    int c  = w >> 10;
    int d = dg * 4 + dl;
    float A_ds = -fexp(Alog[d * D_STATE + s]);
    float Dd = Dp[d];
    float h = hin[((c * 4 + b) * 1024 + d) * 16 + s];
    const int UF = 16;
    for (int i0 = c * CLEN; i0 < (c + 1) * CLEN; i0 += UF) {
        float dtv[UF], uv[UF], Bv[UF], Cv[UF];
        #pragma unroll
        for (int j = 0; j < UF; j++) {
            int i = i0 + j;
            int n = dir ? (NN - 1 - i) : i;
            size_t tt = (size_t)b * NN + n;
            dtv[j] = dt[tt * D_INNER + d];
            uv[j]  = u[tt * D_INNER + d];
            Bv[j]  = xdbl[tt * 64 + 32 + s];
            Cv[j]  = xdbl[tt * 64 + 48 + s];
        }
        float p[UF];
        #pragma unroll
        for (int j = 0; j < UF; j++) {
            float a = fexp(dtv[j] * A_ds);
            h = fmaf(a, h, dtv[j] * Bv[j] * uv[j]);
            p[j] = h * Cv[j];
        }
        #pragma unroll
        for (int j = 0; j < UF; j++) {
            p[j] += __shfl_xor(p[j], 1);
            p[j] += __shfl_xor(p[j], 2);
            p[j] += __shfl_xor(p[j], 4);
            p[j] += __shfl_xor(p[j], 8);
        }
        if (s == 0) {
            #pragma unroll
            for (int j = 0; j < UF; j++) {
                int i = i0 + j;
                int n = dir ? (NN - 1 - i) : i;
                size_t tt = (size_t)b * NN + n;
                float zv = xz[tt * (2 * D_INNER) + D_INNER + d];
                float yv = p[j] + uv[j] * Dd;
                yv *= fsilu(zv);
                y[tt * D_INNER + d] = yv;
            }
        }
    }
}

// ---------------------------------------------------------------------------
extern "C" void kernel_launch(void* const* d_in, const int* in_sizes, int n_in,
                              void* d_out, int out_size, void* d_ws, size_t ws_size,
                              hipStream_t stream) {
    const float* x       = (const float*)d_in[0];
    const float* g1      = (const float*)d_in[1];
    const float* b1      = (const float*)d_in[2];
    const float* g2      = (const float*)d_in[3];
    const float* b2      = (const float*)d_in[4];
    const float* merge_W = (const float*)d_in[5];
    const float* merge_b = (const float*)d_in[6];
    const float* ffn_W1  = (const float*)d_in[7];
    const float* ffn_b1  = (const float*)d_in[8];
    const float* ffn_W2  = (const float*)d_in[9];
    const float* ffn_b2  = (const float*)d_in[10];
    const float* Win[2]   = {(const float*)d_in[11], (const float*)d_in[20]};
    const float* convw[2] = {(const float*)d_in[12], (const float*)d_in[21]};
    const float* convb[2] = {(const float*)d_in[13], (const float*)d_in[22]};
    const float* Wx[2]    = {(const float*)d_in[14], (const float*)d_in[23]};
    const float* Wdt[2]   = {(const float*)d_in[15], (const float*)d_in[24]};
    const float* bdt[2]   = {(const float*)d_in[16], (const float*)d_in[25]};
    const float* Alog[2]  = {(const float*)d_in[17], (const float*)d_in[26]};
    const float* Dp[2]    = {(const float*)d_in[18], (const float*)d_in[27]};
    const float* Wout[2]  = {(const float*)d_in[19], (const float*)d_in[28]};
    float* out = (float*)d_out;

    // workspace layout (floats) — both directions share one buffer set
    float* ws = (float*)d_ws;
    const size_t T = TOK;
    float* xn  = ws;                       // T*512   (reused as xn2 later)
    float* xz  = xn  + T * 512;            // T*2048  (reused as FFN hidden)
    float* uc  = xz  + T * 2048;           // T*1024  (y aliases)
    float* xd  = uc  + T * 1024;           // T*64
    float* dt  = xd  + T * 64;             // T*1024
    float* xfb = dt  + T * 1024;           // T*1024  (concat xf|xb)
    float* x2  = xfb + T * 1024;           // T*512
    // x2 region (T*512 = 1179648 floats) triple-aliased, timeline-disjoint:
    //  - xd4 split-K partials (steps 4-5 of each p)
    //  - scan scratch hend|prodA|hin (step 6 of each p): 3 x 6*65536 floats
    //  - x2 proper (step 8 onward)
    float* xd4   = x2;
    float* hendb = x2;
    float* prodb = x2 + (size_t)NCHUNK * 65536;
    float* hinb  = x2 + (size_t)2 * NCHUNK * 65536;

    // 1. LN1
    ln_kernel<<<TOK, 64, 0, stream>>>(x, g1, b1, xn);

    for (int p = 0; p < 2; p++) {
        // 2. xz = xn @ Win^T   (T x 2048)  [MFMA]
        gemm_mfma<EP_NONE><<<dim3(2048/64, TOK/64), 256, 0, stream>>>(
            xn, 512, Win[p], xz, 2048, nullptr, nullptr, 0, 2048, 512);
        // 3. conv + silu -> uc
        conv_silu_kernel<<<TOK * D_INNER / 256, 256, 0, stream>>>(
            xz, convw[p], convb[p], uc, p);
        // 4. x_dbl = uc @ Wx^T  (T x 64), split-K x4 + reduce
        gemm_wx_splitk<<<dim3(1, TOK/64, 4), 256, 0, stream>>>(uc, Wx[p], xd4);
        reduce4_kernel<<<TOK * 64 / 256, 256, 0, stream>>>(xd4, xd);
        // 5. dt = softplus(dt_raw @ Wdt^T + bdt)  (T x 1024)
        gemm_nt<EP_SOFTPLUS><<<dim3(1024/64, TOK/64), 256, 0, stream>>>(
            xd, 64, Wdt[p], dt, 1024, bdt[p], nullptr, 0, TOK, 1024, 32);
        // 6. chunked selective scan; y aliases uc (chunk-disjoint writes)
        scan_pass1<<<NCHUNK * 256, 256, 0, stream>>>(
            dt, xd, uc, Alog[p], hendb, prodb, p);
        scan_combine<<<256, 256, 0, stream>>>(hendb, prodb, hinb);
        scan_pass2<<<NCHUNK * 256, 256, 0, stream>>>(
            dt, xd, uc, xz, Alog[p], Dp[p], hinb, uc, p);
        // 7. xf/xb = y @ Wout^T  (T x 512) -> halves of xfb  [MFMA]
        gemm_mfma<EP_NONE><<<dim3(512/64, TOK/64), 256, 0, stream>>>(
            uc, 1024, Wout[p], xfb + p * 512, 1024, nullptr, nullptr, 0, 512, 1024);
    }

    // 8. x2 = x + [xf|xb] @ merge_W^T + merge_b  [MFMA]
    gemm_mfma<EP_BIAS_ADD><<<dim3(512/64, TOK/64), 256, 0, stream>>>(
        xfb, 1024, merge_W, x2, 512, merge_b, x, 512, 512, 1024);

    // 9. LN2 (xn buffer reused)
    ln_kernel<<<TOK, 64, 0, stream>>>(x2, g2, b2, xn);

    // 10. h = gelu(xn2 @ ffn_W1^T + b1)   (T x 2048), reuse xz  [MFMA]
    gemm_mfma<EP_GELU><<<dim3(2048/64, TOK/64), 256, 0, stream>>>(
        xn, 512, ffn_W1, xz, 2048, ffn_b1, nullptr, 0, 2048, 512);

    // 11. out = x2 + h @ ffn_W2^T + b2  [MFMA]
    gemm_mfma<EP_BIAS_ADD><<<dim3(512/64, TOK/64), 256, 0, stream>>>(
        xz, 2048, ffn_W2, out, 512, ffn_b2, x2, 512, 512, 2048);
}